// Round 1
// baseline (660.768 us; speedup 1.0000x reference)
//
#include <hip/hip_runtime.h>
#include <math.h>

// ---------------- constants ----------------
#define PHI_F      ((float)1.6180339887498948482045868343656381177)
#define INV_STEP_F ((float)(4096.0 / (2.0 * 3.1415926535897932384626433832795028842)))
#define LUTN 4096
#define B_  8
#define S_  128
#define D_  256
#define H_  8
#define DH_ 32
#define NN_ 256
#define V_  32000
#define M_  (B_ * S_)   // 1024 rows, m = t*8 + b

// Exact replication of lut_sin_cos (f32, unfused ops, mod-4096 like jnp.mod)
__device__ __forceinline__ void lut_sc(float theta,
                                       const float* __restrict__ st,
                                       const float* __restrict__ ct,
                                       float& s, float& c) {
    float pos  = __fmul_rn(theta, INV_STEP_F);
    float i0f  = floorf(pos);
    float frac = __fsub_rn(pos, i0f);
    int i0 = ((int)i0f) & (LUTN - 1);      // two's-complement & == non-negative mod
    int i1 = (i0 + 1) & (LUTN - 1);
    float w0 = __fsub_rn(1.0f, frac);
    s = __fadd_rn(__fmul_rn(st[i0], w0), __fmul_rn(st[i1], frac));
    c = __fadd_rn(__fmul_rn(ct[i0], w0), __fmul_rn(ct[i1], frac));
}

// ---------------- K0: build LUT tables (match np.sin/np.cos f64 -> f32) -----
__global__ void k_tables(float* __restrict__ sin_t, float* __restrict__ cos_t) {
    int i = blockIdx.x * 256 + threadIdx.x;
    if (i < LUTN) {
        double ang = (2.0 * 3.1415926535897932384626433832795028842 * (double)i) / (double)LUTN;
        sin_t[i] = (float)sin(ang);
        cos_t[i] = (float)cos(ang);
    }
}

// ---------------- K1: sequential h-recurrence (2048 independent chains) -----
__global__ __launch_bounds__(256) void k_hscan(
    const int* __restrict__ ids,        // [B,S]
    const float* __restrict__ emb,      // [V, 2D]
    const float* __restrict__ sin_t, const float* __restrict__ cos_t,
    float* __restrict__ hri,            // [M][2D]  (h_r_n | h_i_n)
    float* __restrict__ xbuf)           // [M][D]   x = h_r_n + h_i_n
{
    __shared__ float s_sin[LUTN], s_cos[LUTN];
    for (int i = threadIdx.x; i < LUTN; i += 256) { s_sin[i] = sin_t[i]; s_cos[i] = cos_t[i]; }
    __syncthreads();
    int e = blockIdx.x * 256 + threadIdx.x;   // 0..2047
    int b = e >> 8, d = e & 255;
    float hr = 0.f, hi = 0.f;
    for (int t = 0; t < S_; ++t) {
        int id  = ids[b * S_ + t];
        float w  = emb[(size_t)id * (2 * D_) + d];
        float bt = emb[(size_t)id * (2 * D_) + D_ + d];
        float wl = __fadd_rn(1.0f, fabsf(w));
        float tp = __fmul_rn((float)t, PHI_F);
        float thr_ = __fadd_rn(__fadd_rn(__fdiv_rn(hr, wl), bt), tp);
        float thi_ = __fadd_rn(__fadd_rn(__fdiv_rn(hi, wl), bt), tp);
        float sr, cr, si, ci;
        lut_sc(thr_, s_sin, s_cos, sr, cr);
        lut_sc(thi_, s_sin, s_cos, si, ci);
        float hrn = __fsub_rn(__fmul_rn(cr, ci), __fmul_rn(sr, si));
        float hin = __fadd_rn(__fmul_rn(cr, si), __fmul_rn(sr, ci));
        hr = hrn; hi = hin;
        int m = (t << 3) | b;
        hri[(size_t)m * (2 * D_) + d]        = hrn;
        hri[(size_t)m * (2 * D_) + D_ + d]   = hin;
        xbuf[(size_t)m * D_ + d]             = __fadd_rn(hrn, hin);
    }
}

// ---------------- K2: build Q (with tp) and K (no tp) phase vectors ---------
// q[m][h*64 + j] = cos, [h*64+32+j] = sin  (e: [cq | sq]), same for k.
__global__ void k_qk(const float* __restrict__ xbuf,
                     const float* __restrict__ wq, const float* __restrict__ bq,
                     const float* __restrict__ wk, const float* __restrict__ bk,
                     const float* __restrict__ sin_t, const float* __restrict__ cos_t,
                     float* __restrict__ qbuf, float* __restrict__ kbuf)
{
    int i = blockIdx.x * 256 + threadIdx.x;       // 0 .. 2*S*B*H*DH-1
    const int half = S_ * B_ * H_ * DH_;          // 262144
    bool isq = (i < half);
    int r = isq ? i : i - half;
    if (r >= half) return;
    int j = r & 31;
    int h = (r >> 5) & 7;
    int b = (r >> 8) & 7;
    int t = r >> 11;
    int m = (t << 3) | b;
    float xv = xbuf[(size_t)m * D_ + h * DH_ + j];
    const float* W  = isq ? wq : wk;
    const float* Bv = isq ? bq : bk;
    float wl = __fadd_rn(1.0f, fabsf(W[h * DH_ + j]));
    float th = __fadd_rn(__fdiv_rn(xv, wl), Bv[h * DH_ + j]);
    if (isq) th = __fadd_rn(th, __fmul_rn((float)t, PHI_F));
    float s, c;
    lut_sc(th, sin_t, cos_t, s, c);
    float* out = isq ? qbuf : kbuf;
    out[(size_t)m * (2 * DH_ * H_) + h * 64 + j]      = c;
    out[(size_t)m * (2 * DH_ * H_) + h * 64 + 32 + j] = s;
}

// ---------------- K3: causal phase attention -> ctx[m][D] -------------------
__global__ __launch_bounds__(256) void k_attn(
    const float* __restrict__ qbuf, const float* __restrict__ kbuf,
    const float* __restrict__ xbuf, float* __restrict__ ctx)
{
    int m = blockIdx.x;
    int t = m >> 3, b = m & 7;
    int tid = threadIdx.x;
    if (t == 0) { ctx[(size_t)m * D_ + tid] = 0.f; return; }   // uniform softmax over zero cache
    __shared__ float qs[512];
    __shared__ float sc[8][128];
    __shared__ float denom[8];
    __shared__ float wsum[128];
    qs[tid]       = qbuf[(size_t)m * 512 + tid];
    qs[tid + 256] = qbuf[(size_t)m * 512 + 256 + tid];
    __syncthreads();
    int h = tid & 7;
    for (int s = tid >> 3; s < t; s += 32) {
        const float* kk = kbuf + (size_t)((s << 3) | b) * 512 + h * 64;
        const float* qq = qs + h * 64;
        float dot = 0.f;
        #pragma unroll
        for (int e = 0; e < 64; ++e) dot += qq[e] * kk[e];
        sc[h][s] = dot * 0.125f;   // /sqrt(2*DH)=8 exactly
    }
    __syncthreads();
    if (tid < 8) {
        float mx = -1e30f;
        for (int s = 0; s < t; ++s) mx = fmaxf(mx, sc[tid][s]);
        float dn = 0.f;
        for (int s = 0; s < t; ++s) { float e = expf(sc[tid][s] - mx); sc[tid][s] = e; dn += e; }
        denom[tid] = dn;
    }
    __syncthreads();
    if (tid < t) {
        float wv = 0.f;
        #pragma unroll
        for (int hh = 0; hh < 8; ++hh) wv += sc[hh][tid] / denom[hh];
        wsum[tid] = wv;
    }
    __syncthreads();
    float acc = 0.f;
    for (int s = 0; s < t; ++s) acc += wsum[s] * xbuf[(size_t)((s << 3) | b) * D_ + tid];
    ctx[(size_t)m * D_ + tid] = acc;
}

// ---------------- K4: resonant layer (67M LUT evals) ------------------------
__global__ __launch_bounds__(256) void k_res(
    const float* __restrict__ xc,    // [M][D] (bias already added)
    const float* __restrict__ Wres,  // [NN][D]
    const float* __restrict__ Bres,  // [NN][D]
    const float* __restrict__ sin_t, const float* __restrict__ cos_t,
    float* __restrict__ ct_out, float* __restrict__ st_out)  // [M][NN]
{
    __shared__ float s_sin[LUTN], s_cos[LUTN], s_xc[D_];
    for (int i = threadIdx.x; i < LUTN; i += 256) { s_sin[i] = sin_t[i]; s_cos[i] = cos_t[i]; }
    int m = blockIdx.x;
    s_xc[threadIdx.x] = xc[(size_t)m * D_ + threadIdx.x];
    __syncthreads();
    int n = threadIdx.x;
    int t = m >> 3;
    float tp = __fmul_rn((float)t, PHI_F);
    const float* wr = Wres + (size_t)n * D_;
    const float* br = Bres + (size_t)n * D_;
    float cs = 0.f, ss = 0.f;
    for (int d = 0; d < D_; ++d) {
        float wl = __fadd_rn(1.0f, fabsf(wr[d]));
        float th = __fadd_rn(__fadd_rn(__fdiv_rn(s_xc[d], wl), br[d]), tp);
        float s, c;
        lut_sc(th, s_sin, s_cos, s, c);
        cs += c; ss += s;
    }
    ct_out[(size_t)m * NN_ + n] = cs;
    st_out[(size_t)m * NN_ + n] = ss;
}

// ---------------- K5: pack G=[ctx|ctx|ct|st], BB=[Wr|Wi|Wor|Woi] ------------
__global__ void k_pack(const float* __restrict__ ctx, const float* __restrict__ ct,
                       const float* __restrict__ st,
                       const float* __restrict__ Wr, const float* __restrict__ Wi,
                       const float* __restrict__ Wor, const float* __restrict__ Woi,
                       float* __restrict__ G, float* __restrict__ BB)
{
    int i = blockIdx.x * 256 + threadIdx.x;
    if (i < M_ * 1024) {
        int mm = i >> 10, k = i & 1023;
        float v;
        if (k < 256)      v = ctx[mm * 256 + k];
        else if (k < 512) v = ctx[mm * 256 + k - 256];
        else if (k < 768) v = ct[mm * 256 + k - 512];
        else              v = st[mm * 256 + k - 768];
        G[i] = v;
    } else {
        int r = i - M_ * 1024;
        if (r < 256 * 1024) {
            int n = r >> 10, k = r & 1023;
            float v;
            if (k < 256)      v = Wr[n * 256 + k];
            else if (k < 512) v = Wi[n * 256 + k - 256];
            else if (k < 768) v = Wor[n * 256 + k - 512];
            else              v = Woi[n * 256 + k - 768];
            BB[r] = v;
        }
    }
}

// ---------------- generic f32 NT-GEMM: C[M,N] = A[M,K] * B[N,K]^T (+bias) ---
// out_mode 1: row m -> output row (m&7)*128 + (m>>3)   (the [S,B]->[B,S] transpose)
__global__ __launch_bounds__(256) void gemm_nt(
    const float* __restrict__ A, int lda,
    const float* __restrict__ Bm, int ldb,
    float* __restrict__ C, int ldc,
    const float* __restrict__ bias,
    int K, int out_mode)
{
    __shared__ float As[32][64];
    __shared__ float Bs[32][64];
    const int n0 = blockIdx.x * 64;
    const int m0 = blockIdx.y * 64;
    const int tid = threadIdx.x;
    const int tn = tid & 15, tm = tid >> 4;
    float acc[4][4] = {};
    for (int k0 = 0; k0 < K; k0 += 32) {
        #pragma unroll
        for (int i = 0; i < 2; ++i) {
            int lin = tid + i * 256;          // 0..511
            int r   = lin >> 3;               // 0..63
            int c4  = (lin & 7) * 4;          // 0,4,...,28
            float4 va = *(const float4*)&A[(size_t)(m0 + r) * lda + k0 + c4];
            As[c4 + 0][r] = va.x; As[c4 + 1][r] = va.y; As[c4 + 2][r] = va.z; As[c4 + 3][r] = va.w;
            float4 vb = *(const float4*)&Bm[(size_t)(n0 + r) * ldb + k0 + c4];
            Bs[c4 + 0][r] = vb.x; Bs[c4 + 1][r] = vb.y; Bs[c4 + 2][r] = vb.z; Bs[c4 + 3][r] = vb.w;
        }
        __syncthreads();
        #pragma unroll
        for (int k = 0; k < 32; ++k) {
            const float4 a = *(const float4*)&As[k][tm * 4];
            const float4 b = *(const float4*)&Bs[k][tn * 4];
            const float av[4] = {a.x, a.y, a.z, a.w};
            const float bv[4] = {b.x, b.y, b.z, b.w};
            #pragma unroll
            for (int i = 0; i < 4; ++i)
                #pragma unroll
                for (int j = 0; j < 4; ++j)
                    acc[i][j] += av[i] * bv[j];
        }
        __syncthreads();
    }
    #pragma unroll
    for (int i = 0; i < 4; ++i) {
        int mrow = m0 + tm * 4 + i;
        int orow = out_mode ? ((mrow & 7) * S_ + (mrow >> 3)) : mrow;
        float4 v;
        v.x = acc[i][0]; v.y = acc[i][1]; v.z = acc[i][2]; v.w = acc[i][3];
        if (bias) {
            v.x += bias[n0 + tn * 4 + 0];
            v.y += bias[n0 + tn * 4 + 1];
            v.z += bias[n0 + tn * 4 + 2];
            v.w += bias[n0 + tn * 4 + 3];
        }
        *(float4*)&C[(size_t)orow * ldc + n0 + tn * 4] = v;
    }
}

// ---------------- launcher ----------------
extern "C" void kernel_launch(void* const* d_in, const int* in_sizes, int n_in,
                              void* d_out, int out_size, void* d_ws, size_t ws_size,
                              hipStream_t stream)
{
    const int*   ids  = (const int*)d_in[0];
    const float* emb  = (const float*)d_in[1];
    const float* wq   = (const float*)d_in[2];
    const float* bq   = (const float*)d_in[3];
    const float* wk   = (const float*)d_in[4];
    const float* bk   = (const float*)d_in[5];
    const float* Wr   = (const float*)d_in[6];
    const float* Wi   = (const float*)d_in[7];
    const float* Wc   = (const float*)d_in[8];
    const float* bc   = (const float*)d_in[9];
    const float* Wres = (const float*)d_in[10];
    const float* Bres = (const float*)d_in[11];
    const float* Wor  = (const float*)d_in[12];
    const float* Woi  = (const float*)d_in[13];
    const float* Wout = (const float*)d_in[14];
    float* out = (float*)d_out;
    float* ws  = (float*)d_ws;

    float* sin_t = ws;                      // 4096
    float* cos_t = sin_t + LUTN;            // 4096
    float* hri   = cos_t + LUTN;            // 1024*512
    float* xbuf  = hri  + (size_t)M_ * 512; // 1024*256
    float* qbuf  = xbuf + (size_t)M_ * 256; // 1024*512
    float* kbuf  = qbuf + (size_t)M_ * 512; // 1024*512
    float* ctx   = kbuf + (size_t)M_ * 512; // 1024*256
    float* ct    = ctx  + (size_t)M_ * 256; // 1024*256
    float* st    = ct   + (size_t)M_ * 256; // 1024*256
    float* xc    = st   + (size_t)M_ * 256; // 1024*256
    float* G     = xc   + (size_t)M_ * 256; // 1024*1024
    float* BB    = G    + (size_t)M_ * 1024;// 256*1024
    float* fused = BB   + (size_t)256 * 1024;// 1024*256

    k_tables<<<dim3((LUTN + 255) / 256), dim3(256), 0, stream>>>(sin_t, cos_t);
    k_hscan<<<dim3(8), dim3(256), 0, stream>>>(ids, emb, sin_t, cos_t, hri, xbuf);
    k_qk<<<dim3(2048), dim3(256), 0, stream>>>(xbuf, wq, bq, wk, bk, sin_t, cos_t, qbuf, kbuf);
    k_attn<<<dim3(M_), dim3(256), 0, stream>>>(qbuf, kbuf, xbuf, ctx);
    // xc = [h_r|h_i] @ Wc^T + bc   (M=1024, N=256, K=512)
    gemm_nt<<<dim3(256 / 64, M_ / 64), dim3(256), 0, stream>>>(hri, 512, Wc, 512, xc, 256, bc, 512, 0);
    k_res<<<dim3(M_), dim3(256), 0, stream>>>(xc, Wres, Bres, sin_t, cos_t, ct, st);
    k_pack<<<dim3((M_ * 1024 + 256 * 1024) / 256), dim3(256), 0, stream>>>(ctx, ct, st, Wr, Wi, Wor, Woi, G, BB);
    // fused = G @ BB^T   (M=1024, N=256, K=1024)
    gemm_nt<<<dim3(256 / 64, M_ / 64), dim3(256), 0, stream>>>(G, 1024, BB, 1024, fused, 256, nullptr, 1024, 0);
    // logits = fused @ Wout^T  -> out[b*S*V + t*V + v]   (M=1024, N=32000, K=256)
    gemm_nt<<<dim3(V_ / 64, M_ / 64), dim3(256), 0, stream>>>(fused, 256, Wout, 256, out, V_, nullptr, 256, 1);
}

// Round 2
// 493.836 us; speedup vs baseline: 1.3380x; 1.3380x over previous
//
#include <hip/hip_runtime.h>
#include <math.h>

// ---------------- constants ----------------
#define PHI_F      ((float)1.6180339887498948482045868343656381177)
#define INV_STEP_F ((float)(4096.0 / (2.0 * 3.1415926535897932384626433832795028842)))
#define LUTN 4096
#define B_  8
#define S_  128
#define D_  256
#define H_  8
#define DH_ 32
#define NN_ 256
#define V_  32000
#define M_  (B_ * S_)   // 1024 rows, m = t*8 + b

typedef __attribute__((ext_vector_type(4))) float f32x4;
typedef __attribute__((ext_vector_type(8))) short bf16x8;

// Exact replication of lut_sin_cos (f32, unfused ops, mod-4096 like jnp.mod)
__device__ __forceinline__ void lut_sc(float theta,
                                       const float* __restrict__ st,
                                       const float* __restrict__ ct,
                                       float& s, float& c) {
    float pos  = __fmul_rn(theta, INV_STEP_F);
    float i0f  = floorf(pos);
    float frac = __fsub_rn(pos, i0f);
    int i0 = ((int)i0f) & (LUTN - 1);
    int i1 = (i0 + 1) & (LUTN - 1);
    float w0 = __fsub_rn(1.0f, frac);
    s = __fadd_rn(__fmul_rn(st[i0], w0), __fmul_rn(st[i1], frac));
    c = __fadd_rn(__fmul_rn(ct[i0], w0), __fmul_rn(ct[i1], frac));
}

__device__ __forceinline__ unsigned short f2bf_rne(float x) {
    unsigned u = __float_as_uint(x);
    unsigned r = (u + 0x7FFFu + ((u >> 16) & 1u)) >> 16;
    return (unsigned short)r;
}

// ---------------- K0: build LUT tables ----------------
__global__ void k_tables(float* __restrict__ sin_t, float* __restrict__ cos_t) {
    int i = blockIdx.x * 256 + threadIdx.x;
    if (i < LUTN) {
        double ang = (2.0 * 3.1415926535897932384626433832795028842 * (double)i) / (double)LUTN;
        sin_t[i] = (float)sin(ang);
        cos_t[i] = (float)cos(ang);
    }
}

// ---------------- K1: sequential h-recurrence ----------------
__global__ __launch_bounds__(256) void k_hscan(
    const int* __restrict__ ids, const float* __restrict__ emb,
    const float* __restrict__ sin_t, const float* __restrict__ cos_t,
    float* __restrict__ hri, float* __restrict__ xbuf)
{
    __shared__ float s_sin[LUTN], s_cos[LUTN];
    for (int i = threadIdx.x; i < LUTN; i += 256) { s_sin[i] = sin_t[i]; s_cos[i] = cos_t[i]; }
    __syncthreads();
    int e = blockIdx.x * 256 + threadIdx.x;
    int b = e >> 8, d = e & 255;
    float hr = 0.f, hi = 0.f;
    for (int t = 0; t < S_; ++t) {
        int id  = ids[b * S_ + t];
        float w  = emb[(size_t)id * (2 * D_) + d];
        float bt = emb[(size_t)id * (2 * D_) + D_ + d];
        float wl = __fadd_rn(1.0f, fabsf(w));
        float tp = __fmul_rn((float)t, PHI_F);
        float thr_ = __fadd_rn(__fadd_rn(__fdiv_rn(hr, wl), bt), tp);
        float thi_ = __fadd_rn(__fadd_rn(__fdiv_rn(hi, wl), bt), tp);
        float sr, cr, si, ci;
        lut_sc(thr_, s_sin, s_cos, sr, cr);
        lut_sc(thi_, s_sin, s_cos, si, ci);
        float hrn = __fsub_rn(__fmul_rn(cr, ci), __fmul_rn(sr, si));
        float hin = __fadd_rn(__fmul_rn(cr, si), __fmul_rn(sr, ci));
        hr = hrn; hi = hin;
        int m = (t << 3) | b;
        hri[(size_t)m * (2 * D_) + d]      = hrn;
        hri[(size_t)m * (2 * D_) + D_ + d] = hin;
        xbuf[(size_t)m * D_ + d]           = __fadd_rn(hrn, hin);
    }
}

// ---------------- K2: build Q/K phase vectors ----------------
__global__ void k_qk(const float* __restrict__ xbuf,
                     const float* __restrict__ wq, const float* __restrict__ bq,
                     const float* __restrict__ wk, const float* __restrict__ bk,
                     const float* __restrict__ sin_t, const float* __restrict__ cos_t,
                     float* __restrict__ qbuf, float* __restrict__ kbuf)
{
    int i = blockIdx.x * 256 + threadIdx.x;
    const int half = S_ * B_ * H_ * DH_;
    bool isq = (i < half);
    int r = isq ? i : i - half;
    if (r >= half) return;
    int j = r & 31;
    int h = (r >> 5) & 7;
    int b = (r >> 8) & 7;
    int t = r >> 11;
    int m = (t << 3) | b;
    float xv = xbuf[(size_t)m * D_ + h * DH_ + j];
    const float* W  = isq ? wq : wk;
    const float* Bv = isq ? bq : bk;
    float wl = __fadd_rn(1.0f, fabsf(W[h * DH_ + j]));
    float th = __fadd_rn(__fdiv_rn(xv, wl), Bv[h * DH_ + j]);
    if (isq) th = __fadd_rn(th, __fmul_rn((float)t, PHI_F));
    float s, c;
    lut_sc(th, sin_t, cos_t, s, c);
    float* out = isq ? qbuf : kbuf;
    out[(size_t)m * (2 * DH_ * H_) + h * 64 + j]      = c;
    out[(size_t)m * (2 * DH_ * H_) + h * 64 + 32 + j] = s;
}

// ---------------- K3: causal phase attention ----------------
__global__ __launch_bounds__(256) void k_attn(
    const float* __restrict__ qbuf, const float* __restrict__ kbuf,
    const float* __restrict__ xbuf, float* __restrict__ ctx)
{
    int m = blockIdx.x;
    int t = m >> 3, b = m & 7;
    int tid = threadIdx.x;
    if (t == 0) { ctx[(size_t)m * D_ + tid] = 0.f; return; }
    __shared__ float qs[512];
    __shared__ float sc[8][128];
    __shared__ float denom[8];
    __shared__ float wsum[128];
    qs[tid]       = qbuf[(size_t)m * 512 + tid];
    qs[tid + 256] = qbuf[(size_t)m * 512 + 256 + tid];
    __syncthreads();
    int h = tid & 7;
    for (int s = tid >> 3; s < t; s += 32) {
        const float* kk = kbuf + (size_t)((s << 3) | b) * 512 + h * 64;
        const float* qq = qs + h * 64;
        float dot = 0.f;
        #pragma unroll
        for (int e = 0; e < 64; ++e) dot += qq[e] * kk[e];
        sc[h][s] = dot * 0.125f;
    }
    __syncthreads();
    if (tid < 8) {
        float mx = -1e30f;
        for (int s = 0; s < t; ++s) mx = fmaxf(mx, sc[tid][s]);
        float dn = 0.f;
        for (int s = 0; s < t; ++s) { float e = expf(sc[tid][s] - mx); sc[tid][s] = e; dn += e; }
        denom[tid] = dn;
    }
    __syncthreads();
    if (tid < t) {
        float wv = 0.f;
        #pragma unroll
        for (int hh = 0; hh < 8; ++hh) wv += sc[hh][tid] / denom[hh];
        wsum[tid] = wv;
    }
    __syncthreads();
    float acc = 0.f;
    for (int s = 0; s < t; ++s) acc += wsum[s] * xbuf[(size_t)((s << 3) | b) * D_ + tid];
    ctx[(size_t)m * D_ + tid] = acc;
}

// ---------------- K4: resonant layer ----------------
__global__ __launch_bounds__(256) void k_res(
    const float* __restrict__ xc,
    const float* __restrict__ Wres, const float* __restrict__ Bres,
    const float* __restrict__ sin_t, const float* __restrict__ cos_t,
    float* __restrict__ ct_out, float* __restrict__ st_out)
{
    __shared__ float s_sin[LUTN], s_cos[LUTN], s_xc[D_];
    for (int i = threadIdx.x; i < LUTN; i += 256) { s_sin[i] = sin_t[i]; s_cos[i] = cos_t[i]; }
    int m = blockIdx.x;
    s_xc[threadIdx.x] = xc[(size_t)m * D_ + threadIdx.x];
    __syncthreads();
    int n = threadIdx.x;
    int t = m >> 3;
    float tp = __fmul_rn((float)t, PHI_F);
    const float* wr = Wres + (size_t)n * D_;
    const float* br = Bres + (size_t)n * D_;
    float cs = 0.f, ss = 0.f;
    for (int d = 0; d < D_; ++d) {
        float wl = __fadd_rn(1.0f, fabsf(wr[d]));
        float th = __fadd_rn(__fadd_rn(__fdiv_rn(s_xc[d], wl), br[d]), tp);
        float s, c;
        lut_sc(th, s_sin, s_cos, s, c);
        cs += c; ss += s;
    }
    ct_out[(size_t)m * NN_ + n] = cs;
    st_out[(size_t)m * NN_ + n] = ss;
}

// ---------------- K5: pack G=[ctx|ctx|ct|st], BB=[Wr|Wi|Wor|Woi] ------------
__global__ void k_pack(const float* __restrict__ ctx, const float* __restrict__ ct,
                       const float* __restrict__ st,
                       const float* __restrict__ Wr, const float* __restrict__ Wi,
                       const float* __restrict__ Wor, const float* __restrict__ Woi,
                       float* __restrict__ G, float* __restrict__ BB)
{
    int i = blockIdx.x * 256 + threadIdx.x;
    if (i < M_ * 1024) {
        int mm = i >> 10, k = i & 1023;
        float v;
        if (k < 256)      v = ctx[mm * 256 + k];
        else if (k < 512) v = ctx[mm * 256 + k - 256];
        else if (k < 768) v = ct[mm * 256 + k - 512];
        else              v = st[mm * 256 + k - 768];
        G[i] = v;
    } else {
        int r = i - M_ * 1024;
        if (r < 256 * 1024) {
            int n = r >> 10, k = r & 1023;
            float v;
            if (k < 256)      v = Wr[n * 256 + k];
            else if (k < 512) v = Wi[n * 256 + k - 256];
            else if (k < 768) v = Wor[n * 256 + k - 512];
            else              v = Woi[n * 256 + k - 768];
            BB[r] = v;
        }
    }
}

// ---------------- generic f32 NT-GEMM (small GEMMs only) ----------------
__global__ __launch_bounds__(256) void gemm_nt(
    const float* __restrict__ A, int lda,
    const float* __restrict__ Bm, int ldb,
    float* __restrict__ C, int ldc,
    const float* __restrict__ bias,
    int K, int out_mode)
{
    __shared__ float As[32][64];
    __shared__ float Bs[32][64];
    const int n0 = blockIdx.x * 64;
    const int m0 = blockIdx.y * 64;
    const int tid = threadIdx.x;
    const int tn = tid & 15, tm = tid >> 4;
    float acc[4][4] = {};
    for (int k0 = 0; k0 < K; k0 += 32) {
        #pragma unroll
        for (int i = 0; i < 2; ++i) {
            int lin = tid + i * 256;
            int r   = lin >> 3;
            int c4  = (lin & 7) * 4;
            float4 va = *(const float4*)&A[(size_t)(m0 + r) * lda + k0 + c4];
            As[c4 + 0][r] = va.x; As[c4 + 1][r] = va.y; As[c4 + 2][r] = va.z; As[c4 + 3][r] = va.w;
            float4 vb = *(const float4*)&Bm[(size_t)(n0 + r) * ldb + k0 + c4];
            Bs[c4 + 0][r] = vb.x; Bs[c4 + 1][r] = vb.y; Bs[c4 + 2][r] = vb.z; Bs[c4 + 3][r] = vb.w;
        }
        __syncthreads();
        #pragma unroll
        for (int k = 0; k < 32; ++k) {
            const float4 a = *(const float4*)&As[k][tm * 4];
            const float4 b = *(const float4*)&Bs[k][tn * 4];
            const float av[4] = {a.x, a.y, a.z, a.w};
            const float bv[4] = {b.x, b.y, b.z, b.w};
            #pragma unroll
            for (int i = 0; i < 4; ++i)
                #pragma unroll
                for (int j = 0; j < 4; ++j)
                    acc[i][j] += av[i] * bv[j];
        }
        __syncthreads();
    }
    #pragma unroll
    for (int i = 0; i < 4; ++i) {
        int mrow = m0 + tm * 4 + i;
        int orow = out_mode ? ((mrow & 7) * S_ + (mrow >> 3)) : mrow;
        float4 v;
        v.x = acc[i][0]; v.y = acc[i][1]; v.z = acc[i][2]; v.w = acc[i][3];
        if (bias) {
            v.x += bias[n0 + tn * 4 + 0];
            v.y += bias[n0 + tn * 4 + 1];
            v.z += bias[n0 + tn * 4 + 2];
            v.w += bias[n0 + tn * 4 + 3];
        }
        *(float4*)&C[(size_t)orow * ldc + n0 + tn * 4] = v;
    }
}

// ---------------- K6: f32 -> (bf16 hi, bf16 lo) split, 4 elems/thread ------
__global__ void k_cvt_split(const float* __restrict__ src,
                            unsigned short* __restrict__ h,
                            unsigned short* __restrict__ l, int n)
{
    int i = (blockIdx.x * 256 + threadIdx.x) * 4;
    if (i >= n) return;
    float4 v = *(const float4*)&src[i];
    float xs[4] = {v.x, v.y, v.z, v.w};
    ushort hs[4], ls[4];
    #pragma unroll
    for (int j = 0; j < 4; ++j) {
        ushort hu = f2bf_rne(xs[j]);
        float hf = __uint_as_float(((unsigned)hu) << 16);
        hs[j] = hu;
        ls[j] = f2bf_rne(__fsub_rn(xs[j], hf));
    }
    *(ushort4*)&h[i] = make_ushort4(hs[0], hs[1], hs[2], hs[3]);
    *(ushort4*)&l[i] = make_ushort4(ls[0], ls[1], ls[2], ls[3]);
}

// ---------------- K7: logits GEMM via MFMA bf16 hi/lo split -----------------
// C[m][n] = sum_k A[m][k]*B[n][k], A=[1024][256] (hi,lo), B=[32000][256] (hi,lo)
// out row transpose: orow = (m&7)*128 + (m>>3)
__global__ __launch_bounds__(256) void gemm_logits_mfma(
    const unsigned short* __restrict__ Ah, const unsigned short* __restrict__ Al,
    const unsigned short* __restrict__ Bh, const unsigned short* __restrict__ Bl,
    float* __restrict__ out)
{
    __shared__ unsigned short sAh[128 * 64], sAl[128 * 64];
    __shared__ unsigned short sBh[128 * 64], sBl[128 * 64];
    const int n0 = blockIdx.x * 128;
    const int m0 = blockIdx.y * 128;
    const int tid  = threadIdx.x;
    const int lane = tid & 63;
    const int wv   = tid >> 6;          // 4 waves, 2x2
    const int wr   = wv >> 1, wc = wv & 1;
    f32x4 acc[4][4] = {};

    for (int k0 = 0; k0 < 256; k0 += 64) {
        // stage 4 tiles of [128 rows][64 k] bf16, rule-21: linear LDS dest,
        // inverse-XOR-swizzled global source (slot ^= row&7), swizzled read.
        #pragma unroll
        for (int q = 0; q < 4; ++q) {
            int idx  = q * 256 + tid;          // 0..1023
            int row  = idx >> 3;
            int slot = (idx & 7) ^ (row & 7);
            int ldsbase = (q * 256 + wv * 64) * 8;   // ushort index of wave base
            size_t ga = (size_t)(m0 + row) * 256 + k0 + slot * 8;
            size_t gb = (size_t)(n0 + row) * 256 + k0 + slot * 8;
            __builtin_amdgcn_global_load_lds(
                (const __attribute__((address_space(1))) void*)(Ah + ga),
                (__attribute__((address_space(3))) void*)(sAh + ldsbase), 16, 0, 0);
            __builtin_amdgcn_global_load_lds(
                (const __attribute__((address_space(1))) void*)(Al + ga),
                (__attribute__((address_space(3))) void*)(sAl + ldsbase), 16, 0, 0);
            __builtin_amdgcn_global_load_lds(
                (const __attribute__((address_space(1))) void*)(Bh + gb),
                (__attribute__((address_space(3))) void*)(sBh + ldsbase), 16, 0, 0);
            __builtin_amdgcn_global_load_lds(
                (const __attribute__((address_space(1))) void*)(Bl + gb),
                (__attribute__((address_space(3))) void*)(sBl + ldsbase), 16, 0, 0);
        }
        __syncthreads();

        #pragma unroll
        for (int ks = 0; ks < 2; ++ks) {
            const int kg = ks * 4 + (lane >> 4);
            bf16x8 afh[4], afl[4], bfh[4], bfl[4];
            #pragma unroll
            for (int mi = 0; mi < 4; ++mi) {
                int row  = wr * 64 + mi * 16 + (lane & 15);
                int slot = kg ^ (row & 7);
                afh[mi] = *(const bf16x8*)&sAh[row * 64 + slot * 8];
                afl[mi] = *(const bf16x8*)&sAl[row * 64 + slot * 8];
            }
            #pragma unroll
            for (int nj = 0; nj < 4; ++nj) {
                int row  = wc * 64 + nj * 16 + (lane & 15);
                int slot = kg ^ (row & 7);
                bfh[nj] = *(const bf16x8*)&sBh[row * 64 + slot * 8];
                bfl[nj] = *(const bf16x8*)&sBl[row * 64 + slot * 8];
            }
            #pragma unroll
            for (int mi = 0; mi < 4; ++mi)
                #pragma unroll
                for (int nj = 0; nj < 4; ++nj) {
                    acc[mi][nj] = __builtin_amdgcn_mfma_f32_16x16x32_bf16(afh[mi], bfh[nj], acc[mi][nj], 0, 0, 0);
                    acc[mi][nj] = __builtin_amdgcn_mfma_f32_16x16x32_bf16(afh[mi], bfl[nj], acc[mi][nj], 0, 0, 0);
                    acc[mi][nj] = __builtin_amdgcn_mfma_f32_16x16x32_bf16(afl[mi], bfh[nj], acc[mi][nj], 0, 0, 0);
                }
        }
        __syncthreads();
    }

    #pragma unroll
    for (int mi = 0; mi < 4; ++mi)
        #pragma unroll
        for (int nj = 0; nj < 4; ++nj)
            #pragma unroll
            for (int r = 0; r < 4; ++r) {
                int m = m0 + wr * 64 + mi * 16 + (lane >> 4) * 4 + r;
                int n = n0 + wc * 64 + nj * 16 + (lane & 15);
                int orow = (m & 7) * S_ + (m >> 3);
                out[(size_t)orow * V_ + n] = acc[mi][nj][r];
            }
}

// ---------------- launcher ----------------
extern "C" void kernel_launch(void* const* d_in, const int* in_sizes, int n_in,
                              void* d_out, int out_size, void* d_ws, size_t ws_size,
                              hipStream_t stream)
{
    const int*   ids  = (const int*)d_in[0];
    const float* emb  = (const float*)d_in[1];
    const float* wq   = (const float*)d_in[2];
    const float* bq   = (const float*)d_in[3];
    const float* wk   = (const float*)d_in[4];
    const float* bk   = (const float*)d_in[5];
    const float* Wr   = (const float*)d_in[6];
    const float* Wi   = (const float*)d_in[7];
    const float* Wc   = (const float*)d_in[8];
    const float* bc   = (const float*)d_in[9];
    const float* Wres = (const float*)d_in[10];
    const float* Bres = (const float*)d_in[11];
    const float* Wor  = (const float*)d_in[12];
    const float* Woi  = (const float*)d_in[13];
    const float* Wout = (const float*)d_in[14];
    float* out = (float*)d_out;
    float* ws  = (float*)d_ws;

    float* sin_t = ws;                        // 4096
    float* cos_t = sin_t + LUTN;              // 4096
    float* hri   = cos_t + LUTN;              // 1024*512
    float* xbuf  = hri  + (size_t)M_ * 512;   // 1024*256
    float* qbuf  = xbuf + (size_t)M_ * 256;   // 1024*512
    float* kbuf  = qbuf + (size_t)M_ * 512;   // 1024*512
    float* ctx   = kbuf + (size_t)M_ * 512;   // 1024*256
    float* ct    = ctx  + (size_t)M_ * 256;   // 1024*256
    float* st    = ct   + (size_t)M_ * 256;   // 1024*256
    float* xc    = st   + (size_t)M_ * 256;   // 1024*256
    float* G     = xc   + (size_t)M_ * 256;   // 1024*1024
    float* BB    = G    + (size_t)M_ * 1024;  // 256*1024
    float* fused = BB   + (size_t)256 * 1024; // 1024*256
    // bf16 hi/lo split buffers (ushort), appended after f32 region
    unsigned short* fus_h = (unsigned short*)(fused + (size_t)M_ * 256);
    unsigned short* fus_l = fus_h + (size_t)M_ * 256;                    // 1024*256 each
    unsigned short* Wo_h  = fus_l + (size_t)M_ * 256;
    unsigned short* Wo_l  = Wo_h + (size_t)V_ * 256;                     // 32000*256 each

    k_tables<<<dim3((LUTN + 255) / 256), dim3(256), 0, stream>>>(sin_t, cos_t);
    // Wout split can run early (independent of everything else)
    k_cvt_split<<<dim3((V_ * 256 / 4 + 255) / 256), dim3(256), 0, stream>>>(Wout, Wo_h, Wo_l, V_ * 256);
    k_hscan<<<dim3(8), dim3(256), 0, stream>>>(ids, emb, sin_t, cos_t, hri, xbuf);
    k_qk<<<dim3(2048), dim3(256), 0, stream>>>(xbuf, wq, bq, wk, bk, sin_t, cos_t, qbuf, kbuf);
    k_attn<<<dim3(M_), dim3(256), 0, stream>>>(qbuf, kbuf, xbuf, ctx);
    // xc = [h_r|h_i] @ Wc^T + bc   (M=1024, N=256, K=512)
    gemm_nt<<<dim3(256 / 64, M_ / 64), dim3(256), 0, stream>>>(hri, 512, Wc, 512, xc, 256, bc, 512, 0);
    k_res<<<dim3(M_), dim3(256), 0, stream>>>(xc, Wres, Bres, sin_t, cos_t, ct, st);
    k_pack<<<dim3((M_ * 1024 + 256 * 1024) / 256), dim3(256), 0, stream>>>(ctx, ct, st, Wr, Wi, Wor, Woi, G, BB);
    // fused = G @ BB^T   (M=1024, N=256, K=1024)
    gemm_nt<<<dim3(256 / 64, M_ / 64), dim3(256), 0, stream>>>(G, 1024, BB, 1024, fused, 256, nullptr, 1024, 0);
    k_cvt_split<<<dim3((M_ * 256 / 4 + 255) / 256), dim3(256), 0, stream>>>(fused, fus_h, fus_l, M_ * 256);
    // logits = fused @ Wout^T via bf16x3 MFMA -> out[b*S*V + t*V + v]
    gemm_logits_mfma<<<dim3(V_ / 128, M_ / 128), dim3(256), 0, stream>>>(fus_h, fus_l, Wo_h, Wo_l, out);
}

// Round 3
// 329.343 us; speedup vs baseline: 2.0063x; 1.4995x over previous
//
#include <hip/hip_runtime.h>
#include <math.h>

// ---------------- constants ----------------
#define PHI_F      ((float)1.6180339887498948482045868343656381177)
#define INV_STEP_F ((float)(4096.0 / (2.0 * 3.1415926535897932384626433832795028842)))
#define LUTN 4096
#define B_  8
#define S_  128
#define D_  256
#define H_  8
#define DH_ 32
#define NN_ 256
#define V_  32000
#define M_  (B_ * S_)   // 1024 rows, m = t*8 + b

typedef __attribute__((ext_vector_type(4))) float f32x4;
typedef __attribute__((ext_vector_type(8))) short bf16x8;

// Exact replication of lut_sin_cos (f32, unfused ops, mod-4096 like jnp.mod)
__device__ __forceinline__ void lut_sc(float theta,
                                       const float* __restrict__ st,
                                       const float* __restrict__ ct,
                                       float& s, float& c) {
    float pos  = __fmul_rn(theta, INV_STEP_F);
    float i0f  = floorf(pos);
    float frac = __fsub_rn(pos, i0f);
    int i0 = ((int)i0f) & (LUTN - 1);
    int i1 = (i0 + 1) & (LUTN - 1);
    float w0 = __fsub_rn(1.0f, frac);
    s = __fadd_rn(__fmul_rn(st[i0], w0), __fmul_rn(st[i1], frac));
    c = __fadd_rn(__fmul_rn(ct[i0], w0), __fmul_rn(ct[i1], frac));
}

__device__ __forceinline__ unsigned short f2bf_rne(float x) {
    unsigned u = __float_as_uint(x);
    unsigned r = (u + 0x7FFFu + ((u >> 16) & 1u)) >> 16;
    return (unsigned short)r;
}

// ---------------- K0: build LUT tables ----------------
__global__ void k_tables(float* __restrict__ sin_t, float* __restrict__ cos_t) {
    int i = blockIdx.x * 256 + threadIdx.x;
    if (i < LUTN) {
        double ang = (2.0 * 3.1415926535897932384626433832795028842 * (double)i) / (double)LUTN;
        sin_t[i] = (float)sin(ang);
        cos_t[i] = (float)cos(ang);
    }
}

// ---------------- K1: sequential h-recurrence ----------------
__global__ __launch_bounds__(256) void k_hscan(
    const int* __restrict__ ids, const float* __restrict__ emb,
    const float* __restrict__ sin_t, const float* __restrict__ cos_t,
    float* __restrict__ hri, float* __restrict__ xbuf)
{
    __shared__ float s_sin[LUTN], s_cos[LUTN];
    for (int i = threadIdx.x; i < LUTN; i += 256) { s_sin[i] = sin_t[i]; s_cos[i] = cos_t[i]; }
    __syncthreads();
    int e = blockIdx.x * 256 + threadIdx.x;
    int b = e >> 8, d = e & 255;
    float hr = 0.f, hi = 0.f;
    for (int t = 0; t < S_; ++t) {
        int id  = ids[b * S_ + t];
        float w  = emb[(size_t)id * (2 * D_) + d];
        float bt = emb[(size_t)id * (2 * D_) + D_ + d];
        float wl = __fadd_rn(1.0f, fabsf(w));
        float tp = __fmul_rn((float)t, PHI_F);
        float thr_ = __fadd_rn(__fadd_rn(__fdiv_rn(hr, wl), bt), tp);
        float thi_ = __fadd_rn(__fadd_rn(__fdiv_rn(hi, wl), bt), tp);
        float sr, cr, si, ci;
        lut_sc(thr_, s_sin, s_cos, sr, cr);
        lut_sc(thi_, s_sin, s_cos, si, ci);
        float hrn = __fsub_rn(__fmul_rn(cr, ci), __fmul_rn(sr, si));
        float hin = __fadd_rn(__fmul_rn(cr, si), __fmul_rn(sr, ci));
        hr = hrn; hi = hin;
        int m = (t << 3) | b;
        hri[(size_t)m * (2 * D_) + d]      = hrn;
        hri[(size_t)m * (2 * D_) + D_ + d] = hin;
        xbuf[(size_t)m * D_ + d]           = __fadd_rn(hrn, hin);
    }
}

// ---------------- K2: build Q/K phase vectors ----------------
__global__ void k_qk(const float* __restrict__ xbuf,
                     const float* __restrict__ wq, const float* __restrict__ bq,
                     const float* __restrict__ wk, const float* __restrict__ bk,
                     const float* __restrict__ sin_t, const float* __restrict__ cos_t,
                     float* __restrict__ qbuf, float* __restrict__ kbuf)
{
    int i = blockIdx.x * 256 + threadIdx.x;
    const int half = S_ * B_ * H_ * DH_;
    bool isq = (i < half);
    int r = isq ? i : i - half;
    if (r >= half) return;
    int j = r & 31;
    int h = (r >> 5) & 7;
    int b = (r >> 8) & 7;
    int t = r >> 11;
    int m = (t << 3) | b;
    float xv = xbuf[(size_t)m * D_ + h * DH_ + j];
    const float* W  = isq ? wq : wk;
    const float* Bv = isq ? bq : bk;
    float wl = __fadd_rn(1.0f, fabsf(W[h * DH_ + j]));
    float th = __fadd_rn(__fdiv_rn(xv, wl), Bv[h * DH_ + j]);
    if (isq) th = __fadd_rn(th, __fmul_rn((float)t, PHI_F));
    float s, c;
    lut_sc(th, sin_t, cos_t, s, c);
    float* out = isq ? qbuf : kbuf;
    out[(size_t)m * (2 * DH_ * H_) + h * 64 + j]      = c;
    out[(size_t)m * (2 * DH_ * H_) + h * 64 + 32 + j] = s;
}

// ---------------- K3: causal phase attention ----------------
__global__ __launch_bounds__(256) void k_attn(
    const float* __restrict__ qbuf, const float* __restrict__ kbuf,
    const float* __restrict__ xbuf, float* __restrict__ ctx)
{
    int m = blockIdx.x;
    int t = m >> 3, b = m & 7;
    int tid = threadIdx.x;
    if (t == 0) { ctx[(size_t)m * D_ + tid] = 0.f; return; }
    __shared__ float qs[512];
    __shared__ float sc[8][128];
    __shared__ float denom[8];
    __shared__ float wsum[128];
    qs[tid]       = qbuf[(size_t)m * 512 + tid];
    qs[tid + 256] = qbuf[(size_t)m * 512 + 256 + tid];
    __syncthreads();
    int h = tid & 7;
    for (int s = tid >> 3; s < t; s += 32) {
        const float* kk = kbuf + (size_t)((s << 3) | b) * 512 + h * 64;
        const float* qq = qs + h * 64;
        float dot = 0.f;
        #pragma unroll
        for (int e = 0; e < 64; ++e) dot += qq[e] * kk[e];
        sc[h][s] = dot * 0.125f;
    }
    __syncthreads();
    if (tid < 8) {
        float mx = -1e30f;
        for (int s = 0; s < t; ++s) mx = fmaxf(mx, sc[tid][s]);
        float dn = 0.f;
        for (int s = 0; s < t; ++s) { float e = expf(sc[tid][s] - mx); sc[tid][s] = e; dn += e; }
        denom[tid] = dn;
    }
    __syncthreads();
    if (tid < t) {
        float wv = 0.f;
        #pragma unroll
        for (int hh = 0; hh < 8; ++hh) wv += sc[hh][tid] / denom[hh];
        wsum[tid] = wv;
    }
    __syncthreads();
    float acc = 0.f;
    for (int s = 0; s < t; ++s) acc += wsum[s] * xbuf[(size_t)((s << 3) | b) * D_ + tid];
    ctx[(size_t)m * D_ + tid] = acc;
}

// ---------------- K4a: prep for resonant layer -------------------------------
// winvT[d][n] = 1/(1+|Wres[n][d]|),  bresT[d][n] = Bres[n][d]
__global__ void k_prep_res(const float* __restrict__ Wres, const float* __restrict__ Bres,
                           float* __restrict__ winvT, float* __restrict__ bresT)
{
    int i = blockIdx.x * 256 + threadIdx.x;   // 0..65535, i = n*256+d
    int n = i >> 8, d = i & 255;
    winvT[d * NN_ + n] = 1.0f / (1.0f + fabsf(Wres[i]));
    bresT[d * NN_ + n] = Bres[i];
}

// ---------------- K4b: resonant layer via hw sin/cos ------------------------
// block = 2 consecutive m rows (same t), thread = n.
__global__ __launch_bounds__(256) void k_res2(
    const float* __restrict__ xc,
    const float* __restrict__ winvT, const float* __restrict__ bresT,
    float* __restrict__ ct_out, float* __restrict__ st_out)
{
    __shared__ float s_xc0[D_], s_xc1[D_];
    const int m0 = blockIdx.x * 2;
    const int tid = threadIdx.x;
    s_xc0[tid] = xc[(size_t)m0 * D_ + tid];
    s_xc1[tid] = xc[(size_t)(m0 + 1) * D_ + tid];
    __syncthreads();
    const int n = tid;
    const float tp = __fmul_rn((float)(m0 >> 3), PHI_F);   // m0, m0+1 share t
    float cs0 = 0.f, ss0 = 0.f, cs1 = 0.f, ss1 = 0.f;
    #pragma unroll 4
    for (int d = 0; d < D_; ++d) {
        float wi = winvT[d * NN_ + n];
        float bt = bresT[d * NN_ + n] + tp;
        float th0 = fmaf(s_xc0[d], wi, bt);
        float th1 = fmaf(s_xc1[d], wi, bt);
        cs0 += __cosf(th0); ss0 += __sinf(th0);
        cs1 += __cosf(th1); ss1 += __sinf(th1);
    }
    ct_out[(size_t)m0 * NN_ + n] = cs0;
    st_out[(size_t)m0 * NN_ + n] = ss0;
    ct_out[(size_t)(m0 + 1) * NN_ + n] = cs1;
    st_out[(size_t)(m0 + 1) * NN_ + n] = ss1;
}

// ---------------- K5: pack G=[ctx|ctx|ct|st], BB=[Wr|Wi|Wor|Woi] ------------
__global__ void k_pack(const float* __restrict__ ctx, const float* __restrict__ ct,
                       const float* __restrict__ st,
                       const float* __restrict__ Wr, const float* __restrict__ Wi,
                       const float* __restrict__ Wor, const float* __restrict__ Woi,
                       float* __restrict__ G, float* __restrict__ BB)
{
    int i = blockIdx.x * 256 + threadIdx.x;
    if (i < M_ * 1024) {
        int mm = i >> 10, k = i & 1023;
        float v;
        if (k < 256)      v = ctx[mm * 256 + k];
        else if (k < 512) v = ctx[mm * 256 + k - 256];
        else if (k < 768) v = ct[mm * 256 + k - 512];
        else              v = st[mm * 256 + k - 768];
        G[i] = v;
    } else {
        int r = i - M_ * 1024;
        if (r < 256 * 1024) {
            int n = r >> 10, k = r & 1023;
            float v;
            if (k < 256)      v = Wr[n * 256 + k];
            else if (k < 512) v = Wi[n * 256 + k - 256];
            else if (k < 768) v = Wor[n * 256 + k - 512];
            else              v = Woi[n * 256 + k - 768];
            BB[r] = v;
        }
    }
}

// ---------------- generic f32 NT-GEMM (small GEMMs only) ----------------
__global__ __launch_bounds__(256) void gemm_nt(
    const float* __restrict__ A, int lda,
    const float* __restrict__ Bm, int ldb,
    float* __restrict__ C, int ldc,
    const float* __restrict__ bias,
    int K, int out_mode)
{
    __shared__ float As[32][64];
    __shared__ float Bs[32][64];
    const int n0 = blockIdx.x * 64;
    const int m0 = blockIdx.y * 64;
    const int tid = threadIdx.x;
    const int tn = tid & 15, tm = tid >> 4;
    float acc[4][4] = {};
    for (int k0 = 0; k0 < K; k0 += 32) {
        #pragma unroll
        for (int i = 0; i < 2; ++i) {
            int lin = tid + i * 256;
            int r   = lin >> 3;
            int c4  = (lin & 7) * 4;
            float4 va = *(const float4*)&A[(size_t)(m0 + r) * lda + k0 + c4];
            As[c4 + 0][r] = va.x; As[c4 + 1][r] = va.y; As[c4 + 2][r] = va.z; As[c4 + 3][r] = va.w;
            float4 vb = *(const float4*)&Bm[(size_t)(n0 + r) * ldb + k0 + c4];
            Bs[c4 + 0][r] = vb.x; Bs[c4 + 1][r] = vb.y; Bs[c4 + 2][r] = vb.z; Bs[c4 + 3][r] = vb.w;
        }
        __syncthreads();
        #pragma unroll
        for (int k = 0; k < 32; ++k) {
            const float4 a = *(const float4*)&As[k][tm * 4];
            const float4 b = *(const float4*)&Bs[k][tn * 4];
            const float av[4] = {a.x, a.y, a.z, a.w};
            const float bv[4] = {b.x, b.y, b.z, b.w};
            #pragma unroll
            for (int i = 0; i < 4; ++i)
                #pragma unroll
                for (int j = 0; j < 4; ++j)
                    acc[i][j] += av[i] * bv[j];
        }
        __syncthreads();
    }
    #pragma unroll
    for (int i = 0; i < 4; ++i) {
        int mrow = m0 + tm * 4 + i;
        int orow = out_mode ? ((mrow & 7) * S_ + (mrow >> 3)) : mrow;
        float4 v;
        v.x = acc[i][0]; v.y = acc[i][1]; v.z = acc[i][2]; v.w = acc[i][3];
        if (bias) {
            v.x += bias[n0 + tn * 4 + 0];
            v.y += bias[n0 + tn * 4 + 1];
            v.z += bias[n0 + tn * 4 + 2];
            v.w += bias[n0 + tn * 4 + 3];
        }
        *(float4*)&C[(size_t)orow * ldc + n0 + tn * 4] = v;
    }
}

// ---------------- K6: f32 -> (bf16 hi, bf16 lo) split, 4 elems/thread ------
__global__ void k_cvt_split(const float* __restrict__ src,
                            unsigned short* __restrict__ h,
                            unsigned short* __restrict__ l, int n)
{
    int i = (blockIdx.x * 256 + threadIdx.x) * 4;
    if (i >= n) return;
    float4 v = *(const float4*)&src[i];
    float xs[4] = {v.x, v.y, v.z, v.w};
    ushort hs[4], ls[4];
    #pragma unroll
    for (int j = 0; j < 4; ++j) {
        ushort hu = f2bf_rne(xs[j]);
        float hf = __uint_as_float(((unsigned)hu) << 16);
        hs[j] = hu;
        ls[j] = f2bf_rne(__fsub_rn(xs[j], hf));
    }
    *(ushort4*)&h[i] = make_ushort4(hs[0], hs[1], hs[2], hs[3]);
    *(ushort4*)&l[i] = make_ushort4(ls[0], ls[1], ls[2], ls[3]);
}

// ---------------- K7: logits GEMM via MFMA bf16 hi/lo split -----------------
__global__ __launch_bounds__(256) void gemm_logits_mfma(
    const unsigned short* __restrict__ Ah, const unsigned short* __restrict__ Al,
    const unsigned short* __restrict__ Bh, const unsigned short* __restrict__ Bl,
    float* __restrict__ out)
{
    __shared__ unsigned short sAh[128 * 64], sAl[128 * 64];
    __shared__ unsigned short sBh[128 * 64], sBl[128 * 64];
    const int n0 = blockIdx.x * 128;
    const int m0 = blockIdx.y * 128;
    const int tid  = threadIdx.x;
    const int lane = tid & 63;
    const int wv   = tid >> 6;
    const int wr   = wv >> 1, wc = wv & 1;
    f32x4 acc[4][4] = {};

    for (int k0 = 0; k0 < 256; k0 += 64) {
        #pragma unroll
        for (int q = 0; q < 4; ++q) {
            int idx  = q * 256 + tid;
            int row  = idx >> 3;
            int slot = (idx & 7) ^ (row & 7);
            int ldsbase = (q * 256 + wv * 64) * 8;
            size_t ga = (size_t)(m0 + row) * 256 + k0 + slot * 8;
            size_t gb = (size_t)(n0 + row) * 256 + k0 + slot * 8;
            __builtin_amdgcn_global_load_lds(
                (const __attribute__((address_space(1))) void*)(Ah + ga),
                (__attribute__((address_space(3))) void*)(sAh + ldsbase), 16, 0, 0);
            __builtin_amdgcn_global_load_lds(
                (const __attribute__((address_space(1))) void*)(Al + ga),
                (__attribute__((address_space(3))) void*)(sAl + ldsbase), 16, 0, 0);
            __builtin_amdgcn_global_load_lds(
                (const __attribute__((address_space(1))) void*)(Bh + gb),
                (__attribute__((address_space(3))) void*)(sBh + ldsbase), 16, 0, 0);
            __builtin_amdgcn_global_load_lds(
                (const __attribute__((address_space(1))) void*)(Bl + gb),
                (__attribute__((address_space(3))) void*)(sBl + ldsbase), 16, 0, 0);
        }
        __syncthreads();

        #pragma unroll
        for (int ks = 0; ks < 2; ++ks) {
            const int kg = ks * 4 + (lane >> 4);
            bf16x8 afh[4], afl[4], bfh[4], bfl[4];
            #pragma unroll
            for (int mi = 0; mi < 4; ++mi) {
                int row  = wr * 64 + mi * 16 + (lane & 15);
                int slot = kg ^ (row & 7);
                afh[mi] = *(const bf16x8*)&sAh[row * 64 + slot * 8];
                afl[mi] = *(const bf16x8*)&sAl[row * 64 + slot * 8];
            }
            #pragma unroll
            for (int nj = 0; nj < 4; ++nj) {
                int row  = wc * 64 + nj * 16 + (lane & 15);
                int slot = kg ^ (row & 7);
                bfh[nj] = *(const bf16x8*)&sBh[row * 64 + slot * 8];
                bfl[nj] = *(const bf16x8*)&sBl[row * 64 + slot * 8];
            }
            #pragma unroll
            for (int mi = 0; mi < 4; ++mi)
                #pragma unroll
                for (int nj = 0; nj < 4; ++nj) {
                    acc[mi][nj] = __builtin_amdgcn_mfma_f32_16x16x32_bf16(afh[mi], bfh[nj], acc[mi][nj], 0, 0, 0);
                    acc[mi][nj] = __builtin_amdgcn_mfma_f32_16x16x32_bf16(afh[mi], bfl[nj], acc[mi][nj], 0, 0, 0);
                    acc[mi][nj] = __builtin_amdgcn_mfma_f32_16x16x32_bf16(afl[mi], bfh[nj], acc[mi][nj], 0, 0, 0);
                }
        }
        __syncthreads();
    }

    #pragma unroll
    for (int mi = 0; mi < 4; ++mi)
        #pragma unroll
        for (int nj = 0; nj < 4; ++nj)
            #pragma unroll
            for (int r = 0; r < 4; ++r) {
                int m = m0 + wr * 64 + mi * 16 + (lane >> 4) * 4 + r;
                int n = n0 + wc * 64 + nj * 16 + (lane & 15);
                int orow = (m & 7) * S_ + (m >> 3);
                out[(size_t)orow * V_ + n] = acc[mi][nj][r];
            }
}

// ---------------- launcher ----------------
extern "C" void kernel_launch(void* const* d_in, const int* in_sizes, int n_in,
                              void* d_out, int out_size, void* d_ws, size_t ws_size,
                              hipStream_t stream)
{
    const int*   ids  = (const int*)d_in[0];
    const float* emb  = (const float*)d_in[1];
    const float* wq   = (const float*)d_in[2];
    const float* bq   = (const float*)d_in[3];
    const float* wk   = (const float*)d_in[4];
    const float* bk   = (const float*)d_in[5];
    const float* Wr   = (const float*)d_in[6];
    const float* Wi   = (const float*)d_in[7];
    const float* Wc   = (const float*)d_in[8];
    const float* bc   = (const float*)d_in[9];
    const float* Wres = (const float*)d_in[10];
    const float* Bres = (const float*)d_in[11];
    const float* Wor  = (const float*)d_in[12];
    const float* Woi  = (const float*)d_in[13];
    const float* Wout = (const float*)d_in[14];
    float* out = (float*)d_out;
    float* ws  = (float*)d_ws;

    float* sin_t = ws;                        // 4096
    float* cos_t = sin_t + LUTN;              // 4096
    float* hri   = cos_t + LUTN;              // 1024*512
    float* xbuf  = hri  + (size_t)M_ * 512;   // 1024*256
    float* qbuf  = xbuf + (size_t)M_ * 256;   // 1024*512
    float* kbuf  = qbuf + (size_t)M_ * 512;   // 1024*512
    float* ctx   = kbuf + (size_t)M_ * 512;   // 1024*256
    float* ct    = ctx  + (size_t)M_ * 256;   // 1024*256
    float* st    = ct   + (size_t)M_ * 256;   // 1024*256
    float* xc    = st   + (size_t)M_ * 256;   // 1024*256
    float* G     = xc   + (size_t)M_ * 256;   // 1024*1024
    float* BB    = G    + (size_t)M_ * 1024;  // 256*1024
    float* fused = BB   + (size_t)256 * 1024; // 1024*256
    unsigned short* fus_h = (unsigned short*)(fused + (size_t)M_ * 256);
    unsigned short* fus_l = fus_h + (size_t)M_ * 256;
    unsigned short* Wo_h  = fus_l + (size_t)M_ * 256;
    unsigned short* Wo_l  = Wo_h + (size_t)V_ * 256;
    float* winvT = (float*)(Wo_l + (size_t)V_ * 256);  // 65536
    float* bresT = winvT + (size_t)NN_ * D_;           // 65536

    k_tables<<<dim3((LUTN + 255) / 256), dim3(256), 0, stream>>>(sin_t, cos_t);
    k_cvt_split<<<dim3((V_ * 256 / 4 + 255) / 256), dim3(256), 0, stream>>>(Wout, Wo_h, Wo_l, V_ * 256);
    k_prep_res<<<dim3(NN_ * D_ / 256), dim3(256), 0, stream>>>(Wres, Bres, winvT, bresT);
    k_hscan<<<dim3(8), dim3(256), 0, stream>>>(ids, emb, sin_t, cos_t, hri, xbuf);
    k_qk<<<dim3(2048), dim3(256), 0, stream>>>(xbuf, wq, bq, wk, bk, sin_t, cos_t, qbuf, kbuf);
    k_attn<<<dim3(M_), dim3(256), 0, stream>>>(qbuf, kbuf, xbuf, ctx);
    // xc = [h_r|h_i] @ Wc^T + bc   (M=1024, N=256, K=512)
    gemm_nt<<<dim3(256 / 64, M_ / 64), dim3(256), 0, stream>>>(hri, 512, Wc, 512, xc, 256, bc, 512, 0);
    k_res2<<<dim3(M_ / 2), dim3(256), 0, stream>>>(xc, winvT, bresT, ct, st);
    k_pack<<<dim3((M_ * 1024 + 256 * 1024) / 256), dim3(256), 0, stream>>>(ctx, ct, st, Wr, Wi, Wor, Woi, G, BB);
    // fused = G @ BB^T   (M=1024, N=256, K=1024)
    gemm_nt<<<dim3(256 / 64, M_ / 64), dim3(256), 0, stream>>>(G, 1024, BB, 1024, fused, 256, nullptr, 1024, 0);
    k_cvt_split<<<dim3((M_ * 256 / 4 + 255) / 256), dim3(256), 0, stream>>>(fused, fus_h, fus_l, M_ * 256);
    // logits = fused @ Wout^T via bf16x3 MFMA -> out[b*S*V + t*V + v]
    gemm_logits_mfma<<<dim3(V_ / 128, M_ / 128), dim3(256), 0, stream>>>(fus_h, fus_l, Wo_h, Wo_l, out);
}

// Round 4
// 268.030 us; speedup vs baseline: 2.4653x; 1.2288x over previous
//
#include <hip/hip_runtime.h>
#include <math.h>

// ---------------- constants ----------------
#define PHI_F      ((float)1.6180339887498948482045868343656381177)
#define INV_STEP_F ((float)(4096.0 / (2.0 * 3.1415926535897932384626433832795028842)))
#define LUTN 4096
#define B_  8
#define S_  128
#define D_  256
#define H_  8
#define DH_ 32
#define NN_ 256
#define V_  32000
#define M_  (B_ * S_)   // 1024 rows, m = t*8 + b

typedef __attribute__((ext_vector_type(4))) float f32x4;
typedef __attribute__((ext_vector_type(8))) short bf16x8;

// Exact replication of lut_sin_cos (f32, unfused ops, mod-4096 like jnp.mod)
__device__ __forceinline__ void lut_sc(float theta,
                                       const float* __restrict__ st,
                                       const float* __restrict__ ct,
                                       float& s, float& c) {
    float pos  = __fmul_rn(theta, INV_STEP_F);
    float i0f  = floorf(pos);
    float frac = __fsub_rn(pos, i0f);
    int i0 = ((int)i0f) & (LUTN - 1);
    int i1 = (i0 + 1) & (LUTN - 1);
    float w0 = __fsub_rn(1.0f, frac);
    s = __fadd_rn(__fmul_rn(st[i0], w0), __fmul_rn(st[i1], frac));
    c = __fadd_rn(__fmul_rn(ct[i0], w0), __fmul_rn(ct[i1], frac));
}

__device__ __forceinline__ unsigned short f2bf_rne(float x) {
    unsigned u = __float_as_uint(x);
    unsigned r = (u + 0x7FFFu + ((u >> 16) & 1u)) >> 16;
    return (unsigned short)r;
}

// ---------------- K0: build LUT tables ----------------
__global__ void k_tables(float* __restrict__ sin_t, float* __restrict__ cos_t) {
    int i = blockIdx.x * 256 + threadIdx.x;
    if (i < LUTN) {
        double ang = (2.0 * 3.1415926535897932384626433832795028842 * (double)i) / (double)LUTN;
        sin_t[i] = (float)sin(ang);
        cos_t[i] = (float)cos(ang);
    }
}

// ---------------- K1a: parallel prep for h-recurrence -----------------------
// winv[m][d] = 1/(1+|emb_w|),  cbuf[m][d] = 2*(emb_b + t*PHI)
__global__ __launch_bounds__(256) void k_prep_h(
    const int* __restrict__ ids, const float* __restrict__ emb,
    float* __restrict__ winv, float* __restrict__ cbuf)
{
    int m = blockIdx.x, d = threadIdx.x;
    int t = m >> 3, b = m & 7;
    int id = ids[b * S_ + t];
    float w  = emb[(size_t)id * (2 * D_) + d];
    float bt = emb[(size_t)id * (2 * D_) + D_ + d];
    winv[(size_t)m * D_ + d] = 1.0f / (1.0f + fabsf(w));
    cbuf[(size_t)m * D_ + d] = 2.0f * (bt + (float)t * PHI_F);
}

// ---------------- K1b: sequential h-recurrence (angle form) -----------------
// u_t = x_{t-1}*winv + 2(bt+tp);  h_r = cos u, h_i = sin u, x = cos u + sin u
__global__ __launch_bounds__(64) void k_hscan2(
    const float* __restrict__ winv, const float* __restrict__ cbuf,
    float* __restrict__ hri, float* __restrict__ xbuf)
{
    int e = blockIdx.x * 64 + threadIdx.x;   // 0..2047
    int b = e >> 8, d = e & 255;
    float x = 0.f;
    #pragma unroll 4
    for (int t = 0; t < S_; ++t) {
        int m = (t << 3) | b;
        float wi = winv[(size_t)m * D_ + d];
        float c  = cbuf[(size_t)m * D_ + d];
        float u  = fmaf(x, wi, c);
        float s, co;
        __sincosf(u, &s, &co);
        x = co + s;
        hri[(size_t)m * (2 * D_) + d]      = co;
        hri[(size_t)m * (2 * D_) + D_ + d] = s;
        xbuf[(size_t)m * D_ + d]           = x;
    }
}

// ---------------- K2: build Q/K phase vectors ----------------
__global__ void k_qk(const float* __restrict__ xbuf,
                     const float* __restrict__ wq, const float* __restrict__ bq,
                     const float* __restrict__ wk, const float* __restrict__ bk,
                     const float* __restrict__ sin_t, const float* __restrict__ cos_t,
                     float* __restrict__ qbuf, float* __restrict__ kbuf)
{
    int i = blockIdx.x * 256 + threadIdx.x;
    const int half = S_ * B_ * H_ * DH_;
    bool isq = (i < half);
    int r = isq ? i : i - half;
    if (r >= half) return;
    int j = r & 31;
    int h = (r >> 5) & 7;
    int b = (r >> 8) & 7;
    int t = r >> 11;
    int m = (t << 3) | b;
    float xv = xbuf[(size_t)m * D_ + h * DH_ + j];
    const float* W  = isq ? wq : wk;
    const float* Bv = isq ? bq : bk;
    float wl = __fadd_rn(1.0f, fabsf(W[h * DH_ + j]));
    float th = __fadd_rn(__fdiv_rn(xv, wl), Bv[h * DH_ + j]);
    if (isq) th = __fadd_rn(th, __fmul_rn((float)t, PHI_F));
    float s, c;
    lut_sc(th, sin_t, cos_t, s, c);
    float* out = isq ? qbuf : kbuf;
    out[(size_t)m * (2 * DH_ * H_) + h * 64 + j]      = c;
    out[(size_t)m * (2 * DH_ * H_) + h * 64 + 32 + j] = s;
}

// ---------------- K3: causal phase attention ----------------
__global__ __launch_bounds__(256) void k_attn(
    const float* __restrict__ qbuf, const float* __restrict__ kbuf,
    const float* __restrict__ xbuf, float* __restrict__ ctx)
{
    int m = blockIdx.x;
    int t = m >> 3, b = m & 7;
    int tid = threadIdx.x;
    if (t == 0) { ctx[(size_t)m * D_ + tid] = 0.f; return; }
    __shared__ float qs[512];
    __shared__ float sc[8][128];
    __shared__ float denom[8];
    __shared__ float wsum[128];
    qs[tid]       = qbuf[(size_t)m * 512 + tid];
    qs[tid + 256] = qbuf[(size_t)m * 512 + 256 + tid];
    __syncthreads();
    int h = tid & 7;
    for (int s = tid >> 3; s < t; s += 32) {
        const float* kk = kbuf + (size_t)((s << 3) | b) * 512 + h * 64;
        const float* qq = qs + h * 64;
        float dot = 0.f;
        #pragma unroll
        for (int e = 0; e < 64; ++e) dot += qq[e] * kk[e];
        sc[h][s] = dot * 0.125f;
    }
    __syncthreads();
    if (tid < 8) {
        float mx = -1e30f;
        for (int s = 0; s < t; ++s) mx = fmaxf(mx, sc[tid][s]);
        float dn = 0.f;
        for (int s = 0; s < t; ++s) { float e = expf(sc[tid][s] - mx); sc[tid][s] = e; dn += e; }
        denom[tid] = dn;
    }
    __syncthreads();
    if (tid < t) {
        float wv = 0.f;
        #pragma unroll
        for (int hh = 0; hh < 8; ++hh) wv += sc[hh][tid] / denom[hh];
        wsum[tid] = wv;
    }
    __syncthreads();
    float acc = 0.f;
    for (int s = 0; s < t; ++s) acc += wsum[s] * xbuf[(size_t)((s << 3) | b) * D_ + tid];
    ctx[(size_t)m * D_ + tid] = acc;
}

// ---------------- K4a: prep for resonant layer -------------------------------
__global__ void k_prep_res(const float* __restrict__ Wres, const float* __restrict__ Bres,
                           float* __restrict__ winvT, float* __restrict__ bresT)
{
    int i = blockIdx.x * 256 + threadIdx.x;
    int n = i >> 8, d = i & 255;
    winvT[d * NN_ + n] = 1.0f / (1.0f + fabsf(Wres[i]));
    bresT[d * NN_ + n] = Bres[i];
}

// ---------------- K4b: resonant layer via hw sin/cos ------------------------
__global__ __launch_bounds__(256) void k_res2(
    const float* __restrict__ xc,
    const float* __restrict__ winvT, const float* __restrict__ bresT,
    float* __restrict__ ct_out, float* __restrict__ st_out)
{
    __shared__ float s_xc0[D_], s_xc1[D_];
    const int m0 = blockIdx.x * 2;
    const int tid = threadIdx.x;
    s_xc0[tid] = xc[(size_t)m0 * D_ + tid];
    s_xc1[tid] = xc[(size_t)(m0 + 1) * D_ + tid];
    __syncthreads();
    const int n = tid;
    const float tp = __fmul_rn((float)(m0 >> 3), PHI_F);
    float cs0 = 0.f, ss0 = 0.f, cs1 = 0.f, ss1 = 0.f;
    #pragma unroll 4
    for (int d = 0; d < D_; ++d) {
        float wi = winvT[d * NN_ + n];
        float bt = bresT[d * NN_ + n] + tp;
        float th0 = fmaf(s_xc0[d], wi, bt);
        float th1 = fmaf(s_xc1[d], wi, bt);
        cs0 += __cosf(th0); ss0 += __sinf(th0);
        cs1 += __cosf(th1); ss1 += __sinf(th1);
    }
    ct_out[(size_t)m0 * NN_ + n] = cs0;
    st_out[(size_t)m0 * NN_ + n] = ss0;
    ct_out[(size_t)(m0 + 1) * NN_ + n] = cs1;
    st_out[(size_t)(m0 + 1) * NN_ + n] = ss1;
}

// ---------------- K5: pack G=[ctx|ctx|ct|st], BB=[Wr|Wi|Wor|Woi] ------------
__global__ void k_pack(const float* __restrict__ ctx, const float* __restrict__ ct,
                       const float* __restrict__ st,
                       const float* __restrict__ Wr, const float* __restrict__ Wi,
                       const float* __restrict__ Wor, const float* __restrict__ Woi,
                       float* __restrict__ G, float* __restrict__ BB)
{
    int i = blockIdx.x * 256 + threadIdx.x;
    if (i < M_ * 1024) {
        int mm = i >> 10, k = i & 1023;
        float v;
        if (k < 256)      v = ctx[mm * 256 + k];
        else if (k < 512) v = ctx[mm * 256 + k - 256];
        else if (k < 768) v = ct[mm * 256 + k - 512];
        else              v = st[mm * 256 + k - 768];
        G[i] = v;
    } else {
        int r = i - M_ * 1024;
        if (r < 256 * 1024) {
            int n = r >> 10, k = r & 1023;
            float v;
            if (k < 256)      v = Wr[n * 256 + k];
            else if (k < 512) v = Wi[n * 256 + k - 256];
            else if (k < 768) v = Wor[n * 256 + k - 512];
            else              v = Woi[n * 256 + k - 768];
            BB[r] = v;
        }
    }
}

// ---------------- generic f32 NT-GEMM (small GEMMs only) ----------------
__global__ __launch_bounds__(256) void gemm_nt(
    const float* __restrict__ A, int lda,
    const float* __restrict__ Bm, int ldb,
    float* __restrict__ C, int ldc,
    const float* __restrict__ bias,
    int K, int out_mode)
{
    __shared__ float As[32][64];
    __shared__ float Bs[32][64];
    const int n0 = blockIdx.x * 64;
    const int m0 = blockIdx.y * 64;
    const int tid = threadIdx.x;
    const int tn = tid & 15, tm = tid >> 4;
    float acc[4][4] = {};
    for (int k0 = 0; k0 < K; k0 += 32) {
        #pragma unroll
        for (int i = 0; i < 2; ++i) {
            int lin = tid + i * 256;
            int r   = lin >> 3;
            int c4  = (lin & 7) * 4;
            float4 va = *(const float4*)&A[(size_t)(m0 + r) * lda + k0 + c4];
            As[c4 + 0][r] = va.x; As[c4 + 1][r] = va.y; As[c4 + 2][r] = va.z; As[c4 + 3][r] = va.w;
            float4 vb = *(const float4*)&Bm[(size_t)(n0 + r) * ldb + k0 + c4];
            Bs[c4 + 0][r] = vb.x; Bs[c4 + 1][r] = vb.y; Bs[c4 + 2][r] = vb.z; Bs[c4 + 3][r] = vb.w;
        }
        __syncthreads();
        #pragma unroll
        for (int k = 0; k < 32; ++k) {
            const float4 a = *(const float4*)&As[k][tm * 4];
            const float4 b = *(const float4*)&Bs[k][tn * 4];
            const float av[4] = {a.x, a.y, a.z, a.w};
            const float bv[4] = {b.x, b.y, b.z, b.w};
            #pragma unroll
            for (int i = 0; i < 4; ++i)
                #pragma unroll
                for (int j = 0; j < 4; ++j)
                    acc[i][j] += av[i] * bv[j];
        }
        __syncthreads();
    }
    #pragma unroll
    for (int i = 0; i < 4; ++i) {
        int mrow = m0 + tm * 4 + i;
        int orow = out_mode ? ((mrow & 7) * S_ + (mrow >> 3)) : mrow;
        float4 v;
        v.x = acc[i][0]; v.y = acc[i][1]; v.z = acc[i][2]; v.w = acc[i][3];
        if (bias) {
            v.x += bias[n0 + tn * 4 + 0];
            v.y += bias[n0 + tn * 4 + 1];
            v.z += bias[n0 + tn * 4 + 2];
            v.w += bias[n0 + tn * 4 + 3];
        }
        *(float4*)&C[(size_t)orow * ldc + n0 + tn * 4] = v;
    }
}

// ---------------- K6: f32 -> (bf16 hi, bf16 lo) split ----------------
__global__ void k_cvt_split(const float* __restrict__ src,
                            unsigned short* __restrict__ h,
                            unsigned short* __restrict__ l, int n)
{
    int i = (blockIdx.x * 256 + threadIdx.x) * 4;
    if (i >= n) return;
    float4 v = *(const float4*)&src[i];
    float xs[4] = {v.x, v.y, v.z, v.w};
    ushort hs[4], ls[4];
    #pragma unroll
    for (int j = 0; j < 4; ++j) {
        ushort hu = f2bf_rne(xs[j]);
        float hf = __uint_as_float(((unsigned)hu) << 16);
        hs[j] = hu;
        ls[j] = f2bf_rne(__fsub_rn(xs[j], hf));
    }
    *(ushort4*)&h[i] = make_ushort4(hs[0], hs[1], hs[2], hs[3]);
    *(ushort4*)&l[i] = make_ushort4(ls[0], ls[1], ls[2], ls[3]);
}

// ---------------- K7: logits GEMM via MFMA bf16 hi/lo split -----------------
__global__ __launch_bounds__(256) void gemm_logits_mfma(
    const unsigned short* __restrict__ Ah, const unsigned short* __restrict__ Al,
    const unsigned short* __restrict__ Bh, const unsigned short* __restrict__ Bl,
    float* __restrict__ out)
{
    __shared__ unsigned short sAh[128 * 64], sAl[128 * 64];
    __shared__ unsigned short sBh[128 * 64], sBl[128 * 64];
    const int n0 = blockIdx.x * 128;
    const int m0 = blockIdx.y * 128;
    const int tid  = threadIdx.x;
    const int lane = tid & 63;
    const int wv   = tid >> 6;
    const int wr   = wv >> 1, wc = wv & 1;
    f32x4 acc[4][4] = {};

    for (int k0 = 0; k0 < 256; k0 += 64) {
        #pragma unroll
        for (int q = 0; q < 4; ++q) {
            int idx  = q * 256 + tid;
            int row  = idx >> 3;
            int slot = (idx & 7) ^ (row & 7);
            int ldsbase = (q * 256 + wv * 64) * 8;
            size_t ga = (size_t)(m0 + row) * 256 + k0 + slot * 8;
            size_t gb = (size_t)(n0 + row) * 256 + k0 + slot * 8;
            __builtin_amdgcn_global_load_lds(
                (const __attribute__((address_space(1))) void*)(Ah + ga),
                (__attribute__((address_space(3))) void*)(sAh + ldsbase), 16, 0, 0);
            __builtin_amdgcn_global_load_lds(
                (const __attribute__((address_space(1))) void*)(Al + ga),
                (__attribute__((address_space(3))) void*)(sAl + ldsbase), 16, 0, 0);
            __builtin_amdgcn_global_load_lds(
                (const __attribute__((address_space(1))) void*)(Bh + gb),
                (__attribute__((address_space(3))) void*)(sBh + ldsbase), 16, 0, 0);
            __builtin_amdgcn_global_load_lds(
                (const __attribute__((address_space(1))) void*)(Bl + gb),
                (__attribute__((address_space(3))) void*)(sBl + ldsbase), 16, 0, 0);
        }
        __syncthreads();

        #pragma unroll
        for (int ks = 0; ks < 2; ++ks) {
            const int kg = ks * 4 + (lane >> 4);
            bf16x8 afh[4], afl[4], bfh[4], bfl[4];
            #pragma unroll
            for (int mi = 0; mi < 4; ++mi) {
                int row  = wr * 64 + mi * 16 + (lane & 15);
                int slot = kg ^ (row & 7);
                afh[mi] = *(const bf16x8*)&sAh[row * 64 + slot * 8];
                afl[mi] = *(const bf16x8*)&sAl[row * 64 + slot * 8];
            }
            #pragma unroll
            for (int nj = 0; nj < 4; ++nj) {
                int row  = wc * 64 + nj * 16 + (lane & 15);
                int slot = kg ^ (row & 7);
                bfh[nj] = *(const bf16x8*)&sBh[row * 64 + slot * 8];
                bfl[nj] = *(const bf16x8*)&sBl[row * 64 + slot * 8];
            }
            #pragma unroll
            for (int mi = 0; mi < 4; ++mi)
                #pragma unroll
                for (int nj = 0; nj < 4; ++nj) {
                    acc[mi][nj] = __builtin_amdgcn_mfma_f32_16x16x32_bf16(afh[mi], bfh[nj], acc[mi][nj], 0, 0, 0);
                    acc[mi][nj] = __builtin_amdgcn_mfma_f32_16x16x32_bf16(afh[mi], bfl[nj], acc[mi][nj], 0, 0, 0);
                    acc[mi][nj] = __builtin_amdgcn_mfma_f32_16x16x32_bf16(afl[mi], bfh[nj], acc[mi][nj], 0, 0, 0);
                }
        }
        __syncthreads();
    }

    #pragma unroll
    for (int mi = 0; mi < 4; ++mi)
        #pragma unroll
        for (int nj = 0; nj < 4; ++nj)
            #pragma unroll
            for (int r = 0; r < 4; ++r) {
                int m = m0 + wr * 64 + mi * 16 + (lane >> 4) * 4 + r;
                int n = n0 + wc * 64 + nj * 16 + (lane & 15);
                int orow = (m & 7) * S_ + (m >> 3);
                out[(size_t)orow * V_ + n] = acc[mi][nj][r];
            }
}

// ---------------- launcher ----------------
extern "C" void kernel_launch(void* const* d_in, const int* in_sizes, int n_in,
                              void* d_out, int out_size, void* d_ws, size_t ws_size,
                              hipStream_t stream)
{
    const int*   ids  = (const int*)d_in[0];
    const float* emb  = (const float*)d_in[1];
    const float* wq   = (const float*)d_in[2];
    const float* bq   = (const float*)d_in[3];
    const float* wk   = (const float*)d_in[4];
    const float* bk   = (const float*)d_in[5];
    const float* Wr   = (const float*)d_in[6];
    const float* Wi   = (const float*)d_in[7];
    const float* Wc   = (const float*)d_in[8];
    const float* bc   = (const float*)d_in[9];
    const float* Wres = (const float*)d_in[10];
    const float* Bres = (const float*)d_in[11];
    const float* Wor  = (const float*)d_in[12];
    const float* Woi  = (const float*)d_in[13];
    const float* Wout = (const float*)d_in[14];
    float* out = (float*)d_out;
    float* ws  = (float*)d_ws;

    float* sin_t = ws;                        // 4096
    float* cos_t = sin_t + LUTN;              // 4096
    float* hri   = cos_t + LUTN;              // 1024*512
    float* xbuf  = hri  + (size_t)M_ * 512;   // 1024*256
    float* qbuf  = xbuf + (size_t)M_ * 256;   // 1024*512
    float* kbuf  = qbuf + (size_t)M_ * 512;   // 1024*512
    float* ctx   = kbuf + (size_t)M_ * 512;   // 1024*256
    float* ct    = ctx  + (size_t)M_ * 256;   // 1024*256
    float* st    = ct   + (size_t)M_ * 256;   // 1024*256
    float* xc    = st   + (size_t)M_ * 256;   // 1024*256
    float* G     = xc   + (size_t)M_ * 256;   // 1024*1024
    float* BB    = G    + (size_t)M_ * 1024;  // 256*1024
    float* fused = BB   + (size_t)256 * 1024; // 1024*256
    unsigned short* fus_h = (unsigned short*)(fused + (size_t)M_ * 256);
    unsigned short* fus_l = fus_h + (size_t)M_ * 256;
    unsigned short* Wo_h  = fus_l + (size_t)M_ * 256;
    unsigned short* Wo_l  = Wo_h + (size_t)V_ * 256;
    float* winvT = (float*)(Wo_l + (size_t)V_ * 256);  // 65536
    float* bresT = winvT + (size_t)NN_ * D_;           // 65536
    float* hwinv = bresT + (size_t)NN_ * D_;           // 1024*256
    float* hcbuf = hwinv + (size_t)M_ * D_;            // 1024*256

    k_tables<<<dim3((LUTN + 255) / 256), dim3(256), 0, stream>>>(sin_t, cos_t);
    k_cvt_split<<<dim3((V_ * 256 / 4 + 255) / 256), dim3(256), 0, stream>>>(Wout, Wo_h, Wo_l, V_ * 256);
    k_prep_res<<<dim3(NN_ * D_ / 256), dim3(256), 0, stream>>>(Wres, Bres, winvT, bresT);
    k_prep_h<<<dim3(M_), dim3(256), 0, stream>>>(ids, emb, hwinv, hcbuf);
    k_hscan2<<<dim3(2048 / 64), dim3(64), 0, stream>>>(hwinv, hcbuf, hri, xbuf);
    k_qk<<<dim3(2048), dim3(256), 0, stream>>>(xbuf, wq, bq, wk, bk, sin_t, cos_t, qbuf, kbuf);
    k_attn<<<dim3(M_), dim3(256), 0, stream>>>(qbuf, kbuf, xbuf, ctx);
    // xc = [h_r|h_i] @ Wc^T + bc   (M=1024, N=256, K=512)
    gemm_nt<<<dim3(256 / 64, M_ / 64), dim3(256), 0, stream>>>(hri, 512, Wc, 512, xc, 256, bc, 512, 0);
    k_res2<<<dim3(M_ / 2), dim3(256), 0, stream>>>(xc, winvT, bresT, ct, st);
    k_pack<<<dim3((M_ * 1024 + 256 * 1024) / 256), dim3(256), 0, stream>>>(ctx, ct, st, Wr, Wi, Wor, Woi, G, BB);
    // fused = G @ BB^T   (M=1024, N=256, K=1024)
    gemm_nt<<<dim3(256 / 64, M_ / 64), dim3(256), 0, stream>>>(G, 1024, BB, 1024, fused, 256, nullptr, 1024, 0);
    k_cvt_split<<<dim3((M_ * 256 / 4 + 255) / 256), dim3(256), 0, stream>>>(fused, fus_h, fus_l, M_ * 256);
    // logits = fused @ Wout^T via bf16x3 MFMA -> out[b*S*V + t*V + v]
    gemm_logits_mfma<<<dim3(V_ / 128, M_ / 128), dim3(256), 0, stream>>>(fus_h, fus_l, Wo_h, Wo_l, out);
}

// Round 5
// 261.733 us; speedup vs baseline: 2.5246x; 1.0241x over previous
//
#include <hip/hip_runtime.h>
#include <math.h>

// ---------------- constants ----------------
#define PHI_F      ((float)1.6180339887498948482045868343656381177)
#define INV_STEP_F ((float)(4096.0 / (2.0 * 3.1415926535897932384626433832795028842)))
#define LUTN 4096
#define B_  8
#define S_  128
#define D_  256
#define H_  8
#define DH_ 32
#define NN_ 256
#define V_  32000
#define M_  (B_ * S_)   // 1024 rows, m = t*8 + b

typedef __attribute__((ext_vector_type(4))) float f32x4;
typedef __attribute__((ext_vector_type(8))) short bf16x8;

// Exact replication of lut_sin_cos (f32, unfused ops, mod-4096 like jnp.mod)
__device__ __forceinline__ void lut_sc(float theta,
                                       const float* __restrict__ st,
                                       const float* __restrict__ ct,
                                       float& s, float& c) {
    float pos  = __fmul_rn(theta, INV_STEP_F);
    float i0f  = floorf(pos);
    float frac = __fsub_rn(pos, i0f);
    int i0 = ((int)i0f) & (LUTN - 1);
    int i1 = (i0 + 1) & (LUTN - 1);
    float w0 = __fsub_rn(1.0f, frac);
    s = __fadd_rn(__fmul_rn(st[i0], w0), __fmul_rn(st[i1], frac));
    c = __fadd_rn(__fmul_rn(ct[i0], w0), __fmul_rn(ct[i1], frac));
}

__device__ __forceinline__ unsigned short f2bf_rne(float x) {
    unsigned u = __float_as_uint(x);
    unsigned r = (u + 0x7FFFu + ((u >> 16) & 1u)) >> 16;
    return (unsigned short)r;
}

// ---------------- K0: build LUT tables ----------------
__global__ void k_tables(float* __restrict__ sin_t, float* __restrict__ cos_t) {
    int i = blockIdx.x * 256 + threadIdx.x;
    if (i < LUTN) {
        double ang = (2.0 * 3.1415926535897932384626433832795028842 * (double)i) / (double)LUTN;
        sin_t[i] = (float)sin(ang);
        cos_t[i] = (float)cos(ang);
    }
}

// ---------------- K1a: parallel prep for h-recurrence -----------------------
__global__ __launch_bounds__(256) void k_prep_h(
    const int* __restrict__ ids, const float* __restrict__ emb,
    float* __restrict__ winv, float* __restrict__ cbuf)
{
    int m = blockIdx.x, d = threadIdx.x;
    int t = m >> 3, b = m & 7;
    int id = ids[b * S_ + t];
    float w  = emb[(size_t)id * (2 * D_) + d];
    float bt = emb[(size_t)id * (2 * D_) + D_ + d];
    winv[(size_t)m * D_ + d] = 1.0f / (1.0f + fabsf(w));
    cbuf[(size_t)m * D_ + d] = 2.0f * (bt + (float)t * PHI_F);
}

// ---------------- K1b: sequential h-recurrence (angle form) -----------------
__global__ __launch_bounds__(64) void k_hscan2(
    const float* __restrict__ winv, const float* __restrict__ cbuf,
    float* __restrict__ hri, float* __restrict__ xbuf)
{
    int e = blockIdx.x * 64 + threadIdx.x;   // 0..2047
    int b = e >> 8, d = e & 255;
    float x = 0.f;
    #pragma unroll 4
    for (int t = 0; t < S_; ++t) {
        int m = (t << 3) | b;
        float wi = winv[(size_t)m * D_ + d];
        float c  = cbuf[(size_t)m * D_ + d];
        float u  = fmaf(x, wi, c);
        float s, co;
        __sincosf(u, &s, &co);
        x = co + s;
        hri[(size_t)m * (2 * D_) + d]      = co;
        hri[(size_t)m * (2 * D_) + D_ + d] = s;
        xbuf[(size_t)m * D_ + d]           = x;
    }
}

// ---------------- K2: build Q/K phase vectors ----------------
__global__ void k_qk(const float* __restrict__ xbuf,
                     const float* __restrict__ wq, const float* __restrict__ bq,
                     const float* __restrict__ wk, const float* __restrict__ bk,
                     const float* __restrict__ sin_t, const float* __restrict__ cos_t,
                     float* __restrict__ qbuf, float* __restrict__ kbuf)
{
    int i = blockIdx.x * 256 + threadIdx.x;
    const int half = S_ * B_ * H_ * DH_;
    bool isq = (i < half);
    int r = isq ? i : i - half;
    if (r >= half) return;
    int j = r & 31;
    int h = (r >> 5) & 7;
    int b = (r >> 8) & 7;
    int t = r >> 11;
    int m = (t << 3) | b;
    float xv = xbuf[(size_t)m * D_ + h * DH_ + j];
    const float* W  = isq ? wq : wk;
    const float* Bv = isq ? bq : bk;
    float wl = __fadd_rn(1.0f, fabsf(W[h * DH_ + j]));
    float th = __fadd_rn(__fdiv_rn(xv, wl), Bv[h * DH_ + j]);
    if (isq) th = __fadd_rn(th, __fmul_rn((float)t, PHI_F));
    float s, c;
    lut_sc(th, sin_t, cos_t, s, c);
    float* out = isq ? qbuf : kbuf;
    out[(size_t)m * (2 * DH_ * H_) + h * 64 + j]      = c;
    out[(size_t)m * (2 * DH_ * H_) + h * 64 + 32 + j] = s;
}

// ---------------- K3: causal phase attention ----------------
__global__ __launch_bounds__(256) void k_attn(
    const float* __restrict__ qbuf, const float* __restrict__ kbuf,
    const float* __restrict__ xbuf, float* __restrict__ ctx)
{
    int m = blockIdx.x;
    int t = m >> 3, b = m & 7;
    int tid = threadIdx.x;
    if (t == 0) { ctx[(size_t)m * D_ + tid] = 0.f; return; }
    __shared__ float qs[512];
    __shared__ float sc[8][128];
    __shared__ float denom[8];
    __shared__ float wsum[128];
    qs[tid]       = qbuf[(size_t)m * 512 + tid];
    qs[tid + 256] = qbuf[(size_t)m * 512 + 256 + tid];
    __syncthreads();
    int h = tid & 7;
    for (int s = tid >> 3; s < t; s += 32) {
        const float* kk = kbuf + (size_t)((s << 3) | b) * 512 + h * 64;
        const float* qq = qs + h * 64;
        float dot = 0.f;
        #pragma unroll
        for (int e = 0; e < 64; ++e) dot += qq[e] * kk[e];
        sc[h][s] = dot * 0.125f;
    }
    __syncthreads();
    if (tid < 8) {
        float mx = -1e30f;
        for (int s = 0; s < t; ++s) mx = fmaxf(mx, sc[tid][s]);
        float dn = 0.f;
        for (int s = 0; s < t; ++s) { float e = expf(sc[tid][s] - mx); sc[tid][s] = e; dn += e; }
        denom[tid] = dn;
    }
    __syncthreads();
    if (tid < t) {
        float wv = 0.f;
        #pragma unroll
        for (int hh = 0; hh < 8; ++hh) wv += sc[hh][tid] / denom[hh];
        wsum[tid] = wv;
    }
    __syncthreads();
    float acc = 0.f;
    for (int s = 0; s < t; ++s) acc += wsum[s] * xbuf[(size_t)((s << 3) | b) * D_ + tid];
    ctx[(size_t)m * D_ + tid] = acc;
}

// ---------------- K4a: prep for resonant layer -------------------------------
__global__ void k_prep_res(const float* __restrict__ Wres, const float* __restrict__ Bres,
                           float* __restrict__ winvT, float* __restrict__ bresT)
{
    int i = blockIdx.x * 256 + threadIdx.x;
    int n = i >> 8, d = i & 255;
    winvT[d * NN_ + n] = 1.0f / (1.0f + fabsf(Wres[i]));
    bresT[d * NN_ + n] = Bres[i];
}

// ---------------- K4b: resonant layer via hw sin/cos ------------------------
__global__ __launch_bounds__(256) void k_res2(
    const float* __restrict__ xc,
    const float* __restrict__ winvT, const float* __restrict__ bresT,
    float* __restrict__ ct_out, float* __restrict__ st_out)
{
    __shared__ float s_xc0[D_], s_xc1[D_];
    const int m0 = blockIdx.x * 2;
    const int tid = threadIdx.x;
    s_xc0[tid] = xc[(size_t)m0 * D_ + tid];
    s_xc1[tid] = xc[(size_t)(m0 + 1) * D_ + tid];
    __syncthreads();
    const int n = tid;
    const float tp = __fmul_rn((float)(m0 >> 3), PHI_F);
    float cs0 = 0.f, ss0 = 0.f, cs1 = 0.f, ss1 = 0.f;
    #pragma unroll 4
    for (int d = 0; d < D_; ++d) {
        float wi = winvT[d * NN_ + n];
        float bt = bresT[d * NN_ + n] + tp;
        float th0 = fmaf(s_xc0[d], wi, bt);
        float th1 = fmaf(s_xc1[d], wi, bt);
        cs0 += __cosf(th0); ss0 += __sinf(th0);
        cs1 += __cosf(th1); ss1 += __sinf(th1);
    }
    ct_out[(size_t)m0 * NN_ + n] = cs0;
    st_out[(size_t)m0 * NN_ + n] = ss0;
    ct_out[(size_t)(m0 + 1) * NN_ + n] = cs1;
    st_out[(size_t)(m0 + 1) * NN_ + n] = ss1;
}

// ---------------- K5: pack G=[ctx|ctx|ct|st], BB=[Wr|Wi|Wor|Woi] ------------
__global__ void k_pack(const float* __restrict__ ctx, const float* __restrict__ ct,
                       const float* __restrict__ st,
                       const float* __restrict__ Wr, const float* __restrict__ Wi,
                       const float* __restrict__ Wor, const float* __restrict__ Woi,
                       float* __restrict__ G, float* __restrict__ BB)
{
    int i = blockIdx.x * 256 + threadIdx.x;
    if (i < M_ * 1024) {
        int mm = i >> 10, k = i & 1023;
        float v;
        if (k < 256)      v = ctx[mm * 256 + k];
        else if (k < 512) v = ctx[mm * 256 + k - 256];
        else if (k < 768) v = ct[mm * 256 + k - 512];
        else              v = st[mm * 256 + k - 768];
        G[i] = v;
    } else {
        int r = i - M_ * 1024;
        if (r < 256 * 1024) {
            int n = r >> 10, k = r & 1023;
            float v;
            if (k < 256)      v = Wr[n * 256 + k];
            else if (k < 512) v = Wi[n * 256 + k - 256];
            else if (k < 768) v = Wor[n * 256 + k - 512];
            else              v = Woi[n * 256 + k - 768];
            BB[r] = v;
        }
    }
}

// ---------------- generic f32 NT-GEMM (small GEMMs only) ----------------
__global__ __launch_bounds__(256) void gemm_nt(
    const float* __restrict__ A, int lda,
    const float* __restrict__ Bm, int ldb,
    float* __restrict__ C, int ldc,
    const float* __restrict__ bias,
    int K, int out_mode)
{
    __shared__ float As[32][64];
    __shared__ float Bs[32][64];
    const int n0 = blockIdx.x * 64;
    const int m0 = blockIdx.y * 64;
    const int tid = threadIdx.x;
    const int tn = tid & 15, tm = tid >> 4;
    float acc[4][4] = {};
    for (int k0 = 0; k0 < K; k0 += 32) {
        #pragma unroll
        for (int i = 0; i < 2; ++i) {
            int lin = tid + i * 256;
            int r   = lin >> 3;
            int c4  = (lin & 7) * 4;
            float4 va = *(const float4*)&A[(size_t)(m0 + r) * lda + k0 + c4];
            As[c4 + 0][r] = va.x; As[c4 + 1][r] = va.y; As[c4 + 2][r] = va.z; As[c4 + 3][r] = va.w;
            float4 vb = *(const float4*)&Bm[(size_t)(n0 + r) * ldb + k0 + c4];
            Bs[c4 + 0][r] = vb.x; Bs[c4 + 1][r] = vb.y; Bs[c4 + 2][r] = vb.z; Bs[c4 + 3][r] = vb.w;
        }
        __syncthreads();
        #pragma unroll
        for (int k = 0; k < 32; ++k) {
            const float4 a = *(const float4*)&As[k][tm * 4];
            const float4 b = *(const float4*)&Bs[k][tn * 4];
            const float av[4] = {a.x, a.y, a.z, a.w};
            const float bv[4] = {b.x, b.y, b.z, b.w};
            #pragma unroll
            for (int i = 0; i < 4; ++i)
                #pragma unroll
                for (int j = 0; j < 4; ++j)
                    acc[i][j] += av[i] * bv[j];
        }
        __syncthreads();
    }
    #pragma unroll
    for (int i = 0; i < 4; ++i) {
        int mrow = m0 + tm * 4 + i;
        int orow = out_mode ? ((mrow & 7) * S_ + (mrow >> 3)) : mrow;
        float4 v;
        v.x = acc[i][0]; v.y = acc[i][1]; v.z = acc[i][2]; v.w = acc[i][3];
        if (bias) {
            v.x += bias[n0 + tn * 4 + 0];
            v.y += bias[n0 + tn * 4 + 1];
            v.z += bias[n0 + tn * 4 + 2];
            v.w += bias[n0 + tn * 4 + 3];
        }
        *(float4*)&C[(size_t)orow * ldc + n0 + tn * 4] = v;
    }
}

// ---------------- K6: f32 -> (bf16 hi, bf16 lo) split ----------------
__global__ void k_cvt_split(const float* __restrict__ src,
                            unsigned short* __restrict__ h,
                            unsigned short* __restrict__ l, int n)
{
    int i = (blockIdx.x * 256 + threadIdx.x) * 4;
    if (i >= n) return;
    float4 v = *(const float4*)&src[i];
    float xs[4] = {v.x, v.y, v.z, v.w};
    ushort hs[4], ls[4];
    #pragma unroll
    for (int j = 0; j < 4; ++j) {
        ushort hu = f2bf_rne(xs[j]);
        float hf = __uint_as_float(((unsigned)hu) << 16);
        hs[j] = hu;
        ls[j] = f2bf_rne(__fsub_rn(xs[j], hf));
    }
    *(ushort4*)&h[i] = make_ushort4(hs[0], hs[1], hs[2], hs[3]);
    *(ushort4*)&l[i] = make_ushort4(ls[0], ls[1], ls[2], ls[3]);
}

// ---------------- K7 v2: logits GEMM, in-kernel B split, m-fastest grid -----
// A (fused) pre-split bf16 hi/lo via global_load_lds; B = Wout f32 reg-staged,
// converted with the SAME f2bf_rne split in-kernel (bitwise identical).
// grid: 2000 blocks 1D; m_tile = blk&7 (fastest) so the 8 blocks sharing a
// B-panel are dispatch-adjacent -> B HBM-fetched once.
__global__ __launch_bounds__(256) void gemm_logits2(
    const unsigned short* __restrict__ Ah, const unsigned short* __restrict__ Al,
    const float* __restrict__ Bf, float* __restrict__ out)
{
    __shared__ unsigned short sAh[128 * 64], sAl[128 * 64];
    __shared__ unsigned short sBh[128 * 64], sBl[128 * 64];
    const int blk = blockIdx.x;
    const int m0 = (blk & 7) * 128;
    const int n0 = (blk >> 3) * 128;
    const int tid  = threadIdx.x;
    const int lane = tid & 63;
    const int wv   = tid >> 6;
    const int wr   = wv >> 1, wc = wv & 1;
    const int brow   = tid >> 1;   // 0..127
    const int bkhalf = tid & 1;    // which 32-k half of the 64-k tile
    f32x4 acc[4][4] = {};

    for (int k0 = 0; k0 < 256; k0 += 64) {
        // ---- A: async global->LDS, linear dest + inverse-swizzled source ----
        #pragma unroll
        for (int q = 0; q < 4; ++q) {
            int idx  = q * 256 + tid;
            int row  = idx >> 3;
            int slot = (idx & 7) ^ (row & 7);
            int ldsbase = (q * 256 + wv * 64) * 8;
            size_t ga = (size_t)(m0 + row) * 256 + k0 + slot * 8;
            __builtin_amdgcn_global_load_lds(
                (const __attribute__((address_space(1))) void*)(Ah + ga),
                (__attribute__((address_space(3))) void*)(sAh + ldsbase), 16, 0, 0);
            __builtin_amdgcn_global_load_lds(
                (const __attribute__((address_space(1))) void*)(Al + ga),
                (__attribute__((address_space(3))) void*)(sAl + ldsbase), 16, 0, 0);
        }
        // ---- B: reg-stage f32, split to bf16 hi/lo, swizzled ds_write ----
        #pragma unroll
        for (int g = 0; g < 4; ++g) {
            int kg = bkhalf * 4 + g;                       // k-group of 8
            const float* src = &Bf[(size_t)(n0 + brow) * 256 + k0 + kg * 8];
            float4 v0 = *(const float4*)src;
            float4 v1 = *(const float4*)(src + 4);
            float xs[8] = {v0.x, v0.y, v0.z, v0.w, v1.x, v1.y, v1.z, v1.w};
            bf16x8 h8, l8;
            #pragma unroll
            for (int j = 0; j < 8; ++j) {
                unsigned short hu = f2bf_rne(xs[j]);
                float hf = __uint_as_float(((unsigned)hu) << 16);
                h8[j] = (short)hu;
                l8[j] = (short)f2bf_rne(__fsub_rn(xs[j], hf));
            }
            int off = brow * 64 + (kg ^ (brow & 7)) * 8;
            *(bf16x8*)&sBh[off] = h8;
            *(bf16x8*)&sBl[off] = l8;
        }
        __syncthreads();

        #pragma unroll
        for (int ks = 0; ks < 2; ++ks) {
            const int kg = ks * 4 + (lane >> 4);
            bf16x8 afh[4], afl[4], bfh[4], bfl[4];
            #pragma unroll
            for (int mi = 0; mi < 4; ++mi) {
                int row  = wr * 64 + mi * 16 + (lane & 15);
                int slot = kg ^ (row & 7);
                afh[mi] = *(const bf16x8*)&sAh[row * 64 + slot * 8];
                afl[mi] = *(const bf16x8*)&sAl[row * 64 + slot * 8];
            }
            #pragma unroll
            for (int nj = 0; nj < 4; ++nj) {
                int row  = wc * 64 + nj * 16 + (lane & 15);
                int slot = kg ^ (row & 7);
                bfh[nj] = *(const bf16x8*)&sBh[row * 64 + slot * 8];
                bfl[nj] = *(const bf16x8*)&sBl[row * 64 + slot * 8];
            }
            #pragma unroll
            for (int mi = 0; mi < 4; ++mi)
                #pragma unroll
                for (int nj = 0; nj < 4; ++nj) {
                    acc[mi][nj] = __builtin_amdgcn_mfma_f32_16x16x32_bf16(afh[mi], bfh[nj], acc[mi][nj], 0, 0, 0);
                    acc[mi][nj] = __builtin_amdgcn_mfma_f32_16x16x32_bf16(afh[mi], bfl[nj], acc[mi][nj], 0, 0, 0);
                    acc[mi][nj] = __builtin_amdgcn_mfma_f32_16x16x32_bf16(afl[mi], bfh[nj], acc[mi][nj], 0, 0, 0);
                }
        }
        __syncthreads();
    }

    #pragma unroll
    for (int mi = 0; mi < 4; ++mi)
        #pragma unroll
        for (int nj = 0; nj < 4; ++nj)
            #pragma unroll
            for (int r = 0; r < 4; ++r) {
                int m = m0 + wr * 64 + mi * 16 + (lane >> 4) * 4 + r;
                int n = n0 + wc * 64 + nj * 16 + (lane & 15);
                int orow = (m & 7) * S_ + (m >> 3);
                out[(size_t)orow * V_ + n] = acc[mi][nj][r];
            }
}

// ---------------- launcher ----------------
extern "C" void kernel_launch(void* const* d_in, const int* in_sizes, int n_in,
                              void* d_out, int out_size, void* d_ws, size_t ws_size,
                              hipStream_t stream)
{
    const int*   ids  = (const int*)d_in[0];
    const float* emb  = (const float*)d_in[1];
    const float* wq   = (const float*)d_in[2];
    const float* bq   = (const float*)d_in[3];
    const float* wk   = (const float*)d_in[4];
    const float* bk   = (const float*)d_in[5];
    const float* Wr   = (const float*)d_in[6];
    const float* Wi   = (const float*)d_in[7];
    const float* Wc   = (const float*)d_in[8];
    const float* bc   = (const float*)d_in[9];
    const float* Wres = (const float*)d_in[10];
    const float* Bres = (const float*)d_in[11];
    const float* Wor  = (const float*)d_in[12];
    const float* Woi  = (const float*)d_in[13];
    const float* Wout = (const float*)d_in[14];
    float* out = (float*)d_out;
    float* ws  = (float*)d_ws;

    float* sin_t = ws;                        // 4096
    float* cos_t = sin_t + LUTN;              // 4096
    float* hri   = cos_t + LUTN;              // 1024*512
    float* xbuf  = hri  + (size_t)M_ * 512;   // 1024*256
    float* qbuf  = xbuf + (size_t)M_ * 256;   // 1024*512
    float* kbuf  = qbuf + (size_t)M_ * 512;   // 1024*512
    float* ctx   = kbuf + (size_t)M_ * 512;   // 1024*256
    float* ct    = ctx  + (size_t)M_ * 256;   // 1024*256
    float* st    = ct   + (size_t)M_ * 256;   // 1024*256
    float* xc    = st   + (size_t)M_ * 256;   // 1024*256
    float* G     = xc   + (size_t)M_ * 256;   // 1024*1024
    float* BB    = G    + (size_t)M_ * 1024;  // 256*1024
    float* fused = BB   + (size_t)256 * 1024; // 1024*256
    unsigned short* fus_h = (unsigned short*)(fused + (size_t)M_ * 256);
    unsigned short* fus_l = fus_h + (size_t)M_ * 256;          // 1024*256 each
    float* winvT = (float*)(fus_l + (size_t)M_ * 256);         // 65536
    float* bresT = winvT + (size_t)NN_ * D_;                   // 65536
    float* hwinv = bresT + (size_t)NN_ * D_;                   // 1024*256
    float* hcbuf = hwinv + (size_t)M_ * D_;                    // 1024*256

    k_tables<<<dim3((LUTN + 255) / 256), dim3(256), 0, stream>>>(sin_t, cos_t);
    k_prep_res<<<dim3(NN_ * D_ / 256), dim3(256), 0, stream>>>(Wres, Bres, winvT, bresT);
    k_prep_h<<<dim3(M_), dim3(256), 0, stream>>>(ids, emb, hwinv, hcbuf);
    k_hscan2<<<dim3(2048 / 64), dim3(64), 0, stream>>>(hwinv, hcbuf, hri, xbuf);
    k_qk<<<dim3(2048), dim3(256), 0, stream>>>(xbuf, wq, bq, wk, bk, sin_t, cos_t, qbuf, kbuf);
    k_attn<<<dim3(M_), dim3(256), 0, stream>>>(qbuf, kbuf, xbuf, ctx);
    // xc = [h_r|h_i] @ Wc^T + bc   (M=1024, N=256, K=512)
    gemm_nt<<<dim3(256 / 64, M_ / 64), dim3(256), 0, stream>>>(hri, 512, Wc, 512, xc, 256, bc, 512, 0);
    k_res2<<<dim3(M_ / 2), dim3(256), 0, stream>>>(xc, winvT, bresT, ct, st);
    k_pack<<<dim3((M_ * 1024 + 256 * 1024) / 256), dim3(256), 0, stream>>>(ctx, ct, st, Wr, Wi, Wor, Woi, G, BB);
    // fused = G @ BB^T   (M=1024, N=256, K=1024)
    gemm_nt<<<dim3(256 / 64, M_ / 64), dim3(256), 0, stream>>>(G, 1024, BB, 1024, fused, 256, nullptr, 1024, 0);
    k_cvt_split<<<dim3((M_ * 256 / 4 + 255) / 256), dim3(256), 0, stream>>>(fused, fus_h, fus_l, M_ * 256);
    // logits = fused @ Wout^T via bf16x3 MFMA, in-kernel Wout split
    gemm_logits2<<<dim3((V_ / 128) * (M_ / 128)), dim3(256), 0, stream>>>(fus_h, fus_l, Wout, out);
}

// Round 6
// 240.284 us; speedup vs baseline: 2.7499x; 1.0893x over previous
//
#include <hip/hip_runtime.h>
#include <math.h>

// ---------------- constants ----------------
#define PHI_F      ((float)1.6180339887498948482045868343656381177)
#define INV_STEP_F ((float)(4096.0 / (2.0 * 3.1415926535897932384626433832795028842)))
#define LUTN 4096
#define B_  8
#define S_  128
#define D_  256
#define H_  8
#define DH_ 32
#define NN_ 256
#define V_  32000
#define M_  (B_ * S_)   // 1024 rows, m = t*8 + b

typedef __attribute__((ext_vector_type(4))) float f32x4;
typedef __attribute__((ext_vector_type(8))) short bf16x8;

// Exact replication of lut_sin_cos (f32, unfused ops, mod-4096 like jnp.mod)
__device__ __forceinline__ void lut_sc(float theta,
                                       const float* __restrict__ st,
                                       const float* __restrict__ ct,
                                       float& s, float& c) {
    float pos  = __fmul_rn(theta, INV_STEP_F);
    float i0f  = floorf(pos);
    float frac = __fsub_rn(pos, i0f);
    int i0 = ((int)i0f) & (LUTN - 1);
    int i1 = (i0 + 1) & (LUTN - 1);
    float w0 = __fsub_rn(1.0f, frac);
    s = __fadd_rn(__fmul_rn(st[i0], w0), __fmul_rn(st[i1], frac));
    c = __fadd_rn(__fmul_rn(ct[i0], w0), __fmul_rn(ct[i1], frac));
}

__device__ __forceinline__ unsigned short f2bf_rne(float x) {
    unsigned u = __float_as_uint(x);
    unsigned r = (u + 0x7FFFu + ((u >> 16) & 1u)) >> 16;
    return (unsigned short)r;
}

// ---------------- K0: merged independent preps ------------------------------
// blocks [0,16): LUT tables; [16,272): res prep; [272,1296): h prep;
// [1296,9296): Wout f32 -> bf16 hi/lo split (4 elems/thread)
__global__ __launch_bounds__(256) void k_prep_all(
    const int* __restrict__ ids, const float* __restrict__ emb,
    const float* __restrict__ Wres, const float* __restrict__ Bres,
    const float* __restrict__ Wout,
    float* __restrict__ sin_t, float* __restrict__ cos_t,
    float* __restrict__ winvT, float* __restrict__ bresT,
    float* __restrict__ hwinv, float* __restrict__ hcbuf,
    unsigned short* __restrict__ Wo_h, unsigned short* __restrict__ Wo_l)
{
    const int blk = blockIdx.x;
    const int tid = threadIdx.x;
    if (blk < 16) {
        int i = blk * 256 + tid;
        double ang = (2.0 * 3.1415926535897932384626433832795028842 * (double)i) / (double)LUTN;
        sin_t[i] = (float)sin(ang);
        cos_t[i] = (float)cos(ang);
    } else if (blk < 272) {
        int i = (blk - 16) * 256 + tid;       // i = n*256+d
        int n = i >> 8, d = i & 255;
        winvT[d * NN_ + n] = 1.0f / (1.0f + fabsf(Wres[i]));
        bresT[d * NN_ + n] = Bres[i];
    } else if (blk < 1296) {
        int m = blk - 272, d = tid;
        int t = m >> 3, b = m & 7;
        int id = ids[b * S_ + t];
        float w  = emb[(size_t)id * (2 * D_) + d];
        float bt = emb[(size_t)id * (2 * D_) + D_ + d];
        hwinv[(size_t)m * D_ + d] = 1.0f / (1.0f + fabsf(w));
        hcbuf[(size_t)m * D_ + d] = 2.0f * (bt + (float)t * PHI_F);
    } else {
        int i = ((blk - 1296) * 256 + tid) * 4;    // < V_*256 exactly
        float4 v = *(const float4*)&Wout[i];
        float xs[4] = {v.x, v.y, v.z, v.w};
        ushort hs[4], ls[4];
        #pragma unroll
        for (int j = 0; j < 4; ++j) {
            ushort hu = f2bf_rne(xs[j]);
            float hf = __uint_as_float(((unsigned)hu) << 16);
            hs[j] = hu;
            ls[j] = f2bf_rne(__fsub_rn(xs[j], hf));
        }
        *(ushort4*)&Wo_h[i] = make_ushort4(hs[0], hs[1], hs[2], hs[3]);
        *(ushort4*)&Wo_l[i] = make_ushort4(ls[0], ls[1], ls[2], ls[3]);
    }
}

// ---------------- K1: sequential h-recurrence (angle form) ------------------
__global__ __launch_bounds__(64) void k_hscan2(
    const float* __restrict__ winv, const float* __restrict__ cbuf,
    float* __restrict__ hri, float* __restrict__ xbuf)
{
    int e = blockIdx.x * 64 + threadIdx.x;   // 0..2047
    int b = e >> 8, d = e & 255;
    float x = 0.f;
    #pragma unroll 4
    for (int t = 0; t < S_; ++t) {
        int m = (t << 3) | b;
        float wi = winv[(size_t)m * D_ + d];
        float c  = cbuf[(size_t)m * D_ + d];
        float u  = fmaf(x, wi, c);
        float s, co;
        __sincosf(u, &s, &co);
        x = co + s;
        hri[(size_t)m * (2 * D_) + d]      = co;
        hri[(size_t)m * (2 * D_) + D_ + d] = s;
        xbuf[(size_t)m * D_ + d]           = x;
    }
}

// ---------------- K2: build Q/K phase vectors ----------------
__global__ void k_qk(const float* __restrict__ xbuf,
                     const float* __restrict__ wq, const float* __restrict__ bq,
                     const float* __restrict__ wk, const float* __restrict__ bk,
                     const float* __restrict__ sin_t, const float* __restrict__ cos_t,
                     float* __restrict__ qbuf, float* __restrict__ kbuf)
{
    int i = blockIdx.x * 256 + threadIdx.x;
    const int half = S_ * B_ * H_ * DH_;
    bool isq = (i < half);
    int r = isq ? i : i - half;
    if (r >= half) return;
    int j = r & 31;
    int h = (r >> 5) & 7;
    int b = (r >> 8) & 7;
    int t = r >> 11;
    int m = (t << 3) | b;
    float xv = xbuf[(size_t)m * D_ + h * DH_ + j];
    const float* W  = isq ? wq : wk;
    const float* Bv = isq ? bq : bk;
    float wl = __fadd_rn(1.0f, fabsf(W[h * DH_ + j]));
    float th = __fadd_rn(__fdiv_rn(xv, wl), Bv[h * DH_ + j]);
    if (isq) th = __fadd_rn(th, __fmul_rn((float)t, PHI_F));
    float s, c;
    lut_sc(th, sin_t, cos_t, s, c);
    float* out = isq ? qbuf : kbuf;
    out[(size_t)m * (2 * DH_ * H_) + h * 64 + j]      = c;
    out[(size_t)m * (2 * DH_ * H_) + h * 64 + 32 + j] = s;
}

// ---------------- K3: causal phase attention ----------------
__global__ __launch_bounds__(256) void k_attn(
    const float* __restrict__ qbuf, const float* __restrict__ kbuf,
    const float* __restrict__ xbuf, float* __restrict__ ctx)
{
    int m = blockIdx.x;
    int t = m >> 3, b = m & 7;
    int tid = threadIdx.x;
    if (t == 0) { ctx[(size_t)m * D_ + tid] = 0.f; return; }
    __shared__ float qs[512];
    __shared__ float sc[8][128];
    __shared__ float denom[8];
    __shared__ float wsum[128];
    qs[tid]       = qbuf[(size_t)m * 512 + tid];
    qs[tid + 256] = qbuf[(size_t)m * 512 + 256 + tid];
    __syncthreads();
    int h = tid & 7;
    for (int s = tid >> 3; s < t; s += 32) {
        const float* kk = kbuf + (size_t)((s << 3) | b) * 512 + h * 64;
        const float* qq = qs + h * 64;
        float dot = 0.f;
        #pragma unroll
        for (int e = 0; e < 64; ++e) dot += qq[e] * kk[e];
        sc[h][s] = dot * 0.125f;
    }
    __syncthreads();
    if (tid < 8) {
        float mx = -1e30f;
        for (int s = 0; s < t; ++s) mx = fmaxf(mx, sc[tid][s]);
        float dn = 0.f;
        for (int s = 0; s < t; ++s) { float e = expf(sc[tid][s] - mx); sc[tid][s] = e; dn += e; }
        denom[tid] = dn;
    }
    __syncthreads();
    if (tid < t) {
        float wv = 0.f;
        #pragma unroll
        for (int hh = 0; hh < 8; ++hh) wv += sc[hh][tid] / denom[hh];
        wsum[tid] = wv;
    }
    __syncthreads();
    float a0 = 0.f, a1 = 0.f, a2 = 0.f, a3 = 0.f;
    int s = 0;
    for (; s + 4 <= t; s += 4) {
        a0 += wsum[s + 0] * xbuf[(size_t)(((s + 0) << 3) | b) * D_ + tid];
        a1 += wsum[s + 1] * xbuf[(size_t)(((s + 1) << 3) | b) * D_ + tid];
        a2 += wsum[s + 2] * xbuf[(size_t)(((s + 2) << 3) | b) * D_ + tid];
        a3 += wsum[s + 3] * xbuf[(size_t)(((s + 3) << 3) | b) * D_ + tid];
    }
    for (; s < t; ++s) a0 += wsum[s] * xbuf[(size_t)((s << 3) | b) * D_ + tid];
    ctx[(size_t)m * D_ + tid] = (a0 + a1) + (a2 + a3);
}

// ---------------- K4: resonant layer via hw sin/cos ------------------------
__global__ __launch_bounds__(256) void k_res2(
    const float* __restrict__ xc,
    const float* __restrict__ winvT, const float* __restrict__ bresT,
    float* __restrict__ ct_out, float* __restrict__ st_out)
{
    __shared__ float s_xc0[D_], s_xc1[D_];
    const int m0 = blockIdx.x * 2;
    const int tid = threadIdx.x;
    s_xc0[tid] = xc[(size_t)m0 * D_ + tid];
    s_xc1[tid] = xc[(size_t)(m0 + 1) * D_ + tid];
    __syncthreads();
    const int n = tid;
    const float tp = __fmul_rn((float)(m0 >> 3), PHI_F);
    float cs0 = 0.f, ss0 = 0.f, cs1 = 0.f, ss1 = 0.f;
    #pragma unroll 4
    for (int d = 0; d < D_; ++d) {
        float wi = winvT[d * NN_ + n];
        float bt = bresT[d * NN_ + n] + tp;
        float th0 = fmaf(s_xc0[d], wi, bt);
        float th1 = fmaf(s_xc1[d], wi, bt);
        cs0 += __cosf(th0); ss0 += __sinf(th0);
        cs1 += __cosf(th1); ss1 += __sinf(th1);
    }
    ct_out[(size_t)m0 * NN_ + n] = cs0;
    st_out[(size_t)m0 * NN_ + n] = ss0;
    ct_out[(size_t)(m0 + 1) * NN_ + n] = cs1;
    st_out[(size_t)(m0 + 1) * NN_ + n] = ss1;
}

// ---------------- K5: pack G=[ctx|ctx|ct|st], BB=[Wr|Wi|Wor|Woi] ------------
__global__ void k_pack(const float* __restrict__ ctx, const float* __restrict__ ct,
                       const float* __restrict__ st,
                       const float* __restrict__ Wr, const float* __restrict__ Wi,
                       const float* __restrict__ Wor, const float* __restrict__ Woi,
                       float* __restrict__ G, float* __restrict__ BB)
{
    int i = blockIdx.x * 256 + threadIdx.x;
    if (i < M_ * 1024) {
        int mm = i >> 10, k = i & 1023;
        float v;
        if (k < 256)      v = ctx[mm * 256 + k];
        else if (k < 512) v = ctx[mm * 256 + k - 256];
        else if (k < 768) v = ct[mm * 256 + k - 512];
        else              v = st[mm * 256 + k - 768];
        G[i] = v;
    } else {
        int r = i - M_ * 1024;
        if (r < 256 * 1024) {
            int n = r >> 10, k = r & 1023;
            float v;
            if (k < 256)      v = Wr[n * 256 + k];
            else if (k < 512) v = Wi[n * 256 + k - 256];
            else if (k < 768) v = Wor[n * 256 + k - 512];
            else              v = Woi[n * 256 + k - 768];
            BB[r] = v;
        }
    }
}

// ---------------- generic f32 NT-GEMM ----------------
// out_mode 0: f32 C write (+bias). out_mode 2: write bf16 hi/lo split of acc
// (bitwise identical to the old separate k_cvt_split pass).
__global__ __launch_bounds__(256) void gemm_nt(
    const float* __restrict__ A, int lda,
    const float* __restrict__ Bm, int ldb,
    float* __restrict__ C, int ldc,
    const float* __restrict__ bias,
    int K, int out_mode,
    unsigned short* __restrict__ Oh, unsigned short* __restrict__ Ol)
{
    __shared__ float As[32][64];
    __shared__ float Bs[32][64];
    const int n0 = blockIdx.x * 64;
    const int m0 = blockIdx.y * 64;
    const int tid = threadIdx.x;
    const int tn = tid & 15, tm = tid >> 4;
    float acc[4][4] = {};
    for (int k0 = 0; k0 < K; k0 += 32) {
        #pragma unroll
        for (int i = 0; i < 2; ++i) {
            int lin = tid + i * 256;
            int r   = lin >> 3;
            int c4  = (lin & 7) * 4;
            float4 va = *(const float4*)&A[(size_t)(m0 + r) * lda + k0 + c4];
            As[c4 + 0][r] = va.x; As[c4 + 1][r] = va.y; As[c4 + 2][r] = va.z; As[c4 + 3][r] = va.w;
            float4 vb = *(const float4*)&Bm[(size_t)(n0 + r) * ldb + k0 + c4];
            Bs[c4 + 0][r] = vb.x; Bs[c4 + 1][r] = vb.y; Bs[c4 + 2][r] = vb.z; Bs[c4 + 3][r] = vb.w;
        }
        __syncthreads();
        #pragma unroll
        for (int k = 0; k < 32; ++k) {
            const float4 a = *(const float4*)&As[k][tm * 4];
            const float4 b = *(const float4*)&Bs[k][tn * 4];
            const float av[4] = {a.x, a.y, a.z, a.w};
            const float bv[4] = {b.x, b.y, b.z, b.w};
            #pragma unroll
            for (int i = 0; i < 4; ++i)
                #pragma unroll
                for (int j = 0; j < 4; ++j)
                    acc[i][j] += av[i] * bv[j];
        }
        __syncthreads();
    }
    #pragma unroll
    for (int i = 0; i < 4; ++i) {
        int mrow = m0 + tm * 4 + i;
        if (out_mode == 2) {
            ushort hs[4], ls[4];
            #pragma unroll
            for (int j = 0; j < 4; ++j) {
                float x = acc[i][j];
                ushort hu = f2bf_rne(x);
                float hf = __uint_as_float(((unsigned)hu) << 16);
                hs[j] = hu;
                ls[j] = f2bf_rne(__fsub_rn(x, hf));
            }
            *(ushort4*)&Oh[(size_t)mrow * ldc + n0 + tn * 4] = make_ushort4(hs[0], hs[1], hs[2], hs[3]);
            *(ushort4*)&Ol[(size_t)mrow * ldc + n0 + tn * 4] = make_ushort4(ls[0], ls[1], ls[2], ls[3]);
        } else {
            float4 v;
            v.x = acc[i][0]; v.y = acc[i][1]; v.z = acc[i][2]; v.w = acc[i][3];
            if (bias) {
                v.x += bias[n0 + tn * 4 + 0];
                v.y += bias[n0 + tn * 4 + 1];
                v.z += bias[n0 + tn * 4 + 2];
                v.w += bias[n0 + tn * 4 + 3];
            }
            *(float4*)&C[(size_t)mrow * ldc + n0 + tn * 4] = v;
        }
    }
}

// ---------------- K7 v3: logits GEMM, XCD-panel-grouped ordering ------------
// blk = j*64 + m*8 + r ; panel p = j*8 + r ; m-tile = m.
// With round-robin blk%8 -> XCD, all 8 m-tiles of panel p land on XCD r,
// dispatch-adjacent -> the B panel is fetched into that XCD's L2 once.
__global__ __launch_bounds__(256) void gemm_logits3(
    const unsigned short* __restrict__ Ah, const unsigned short* __restrict__ Al,
    const unsigned short* __restrict__ Bh, const unsigned short* __restrict__ Bl,
    float* __restrict__ out)
{
    const int blk = blockIdx.x;
    const int r = blk & 7, mt = (blk >> 3) & 7, j = blk >> 6;
    const int p = j * 8 + r;
    if (p >= V_ / 128) return;
    const int n0 = p * 128;
    const int m0 = mt * 128;

    __shared__ unsigned short sAh[128 * 64], sAl[128 * 64];
    __shared__ unsigned short sBh[128 * 64], sBl[128 * 64];
    const int tid  = threadIdx.x;
    const int lane = tid & 63;
    const int wv   = tid >> 6;
    const int wr   = wv >> 1, wc = wv & 1;
    f32x4 acc[4][4] = {};

    for (int k0 = 0; k0 < 256; k0 += 64) {
        #pragma unroll
        for (int q = 0; q < 4; ++q) {
            int idx  = q * 256 + tid;
            int row  = idx >> 3;
            int slot = (idx & 7) ^ (row & 7);
            int ldsbase = (q * 256 + wv * 64) * 8;
            size_t ga = (size_t)(m0 + row) * 256 + k0 + slot * 8;
            size_t gb = (size_t)(n0 + row) * 256 + k0 + slot * 8;
            __builtin_amdgcn_global_load_lds(
                (const __attribute__((address_space(1))) void*)(Ah + ga),
                (__attribute__((address_space(3))) void*)(sAh + ldsbase), 16, 0, 0);
            __builtin_amdgcn_global_load_lds(
                (const __attribute__((address_space(1))) void*)(Al + ga),
                (__attribute__((address_space(3))) void*)(sAl + ldsbase), 16, 0, 0);
            __builtin_amdgcn_global_load_lds(
                (const __attribute__((address_space(1))) void*)(Bh + gb),
                (__attribute__((address_space(3))) void*)(sBh + ldsbase), 16, 0, 0);
            __builtin_amdgcn_global_load_lds(
                (const __attribute__((address_space(1))) void*)(Bl + gb),
                (__attribute__((address_space(3))) void*)(sBl + ldsbase), 16, 0, 0);
        }
        __syncthreads();

        #pragma unroll
        for (int ks = 0; ks < 2; ++ks) {
            const int kg = ks * 4 + (lane >> 4);
            bf16x8 afh[4], afl[4], bfh[4], bfl[4];
            #pragma unroll
            for (int mi = 0; mi < 4; ++mi) {
                int row  = wr * 64 + mi * 16 + (lane & 15);
                int slot = kg ^ (row & 7);
                afh[mi] = *(const bf16x8*)&sAh[row * 64 + slot * 8];
                afl[mi] = *(const bf16x8*)&sAl[row * 64 + slot * 8];
            }
            #pragma unroll
            for (int nj = 0; nj < 4; ++nj) {
                int row  = wc * 64 + nj * 16 + (lane & 15);
                int slot = kg ^ (row & 7);
                bfh[nj] = *(const bf16x8*)&sBh[row * 64 + slot * 8];
                bfl[nj] = *(const bf16x8*)&sBl[row * 64 + slot * 8];
            }
            #pragma unroll
            for (int mi = 0; mi < 4; ++mi)
                #pragma unroll
                for (int nj = 0; nj < 4; ++nj) {
                    acc[mi][nj] = __builtin_amdgcn_mfma_f32_16x16x32_bf16(afh[mi], bfh[nj], acc[mi][nj], 0, 0, 0);
                    acc[mi][nj] = __builtin_amdgcn_mfma_f32_16x16x32_bf16(afh[mi], bfl[nj], acc[mi][nj], 0, 0, 0);
                    acc[mi][nj] = __builtin_amdgcn_mfma_f32_16x16x32_bf16(afl[mi], bfh[nj], acc[mi][nj], 0, 0, 0);
                }
        }
        __syncthreads();
    }

    #pragma unroll
    for (int mi = 0; mi < 4; ++mi)
        #pragma unroll
        for (int nj = 0; nj < 4; ++nj)
            #pragma unroll
            for (int rr = 0; rr < 4; ++rr) {
                int m = m0 + wr * 64 + mi * 16 + (lane >> 4) * 4 + rr;
                int n = n0 + wc * 64 + nj * 16 + (lane & 15);
                int orow = (m & 7) * S_ + (m >> 3);
                out[(size_t)orow * V_ + n] = acc[mi][nj][rr];
            }
}

// ---------------- launcher ----------------
extern "C" void kernel_launch(void* const* d_in, const int* in_sizes, int n_in,
                              void* d_out, int out_size, void* d_ws, size_t ws_size,
                              hipStream_t stream)
{
    const int*   ids  = (const int*)d_in[0];
    const float* emb  = (const float*)d_in[1];
    const float* wq   = (const float*)d_in[2];
    const float* bq   = (const float*)d_in[3];
    const float* wk   = (const float*)d_in[4];
    const float* bk   = (const float*)d_in[5];
    const float* Wr   = (const float*)d_in[6];
    const float* Wi   = (const float*)d_in[7];
    const float* Wc   = (const float*)d_in[8];
    const float* bc   = (const float*)d_in[9];
    const float* Wres = (const float*)d_in[10];
    const float* Bres = (const float*)d_in[11];
    const float* Wor  = (const float*)d_in[12];
    const float* Woi  = (const float*)d_in[13];
    const float* Wout = (const float*)d_in[14];
    float* out = (float*)d_out;
    float* ws  = (float*)d_ws;

    float* sin_t = ws;                        // 4096
    float* cos_t = sin_t + LUTN;              // 4096
    float* hri   = cos_t + LUTN;              // 1024*512
    float* xbuf  = hri  + (size_t)M_ * 512;   // 1024*256
    float* qbuf  = xbuf + (size_t)M_ * 256;   // 1024*512
    float* kbuf  = qbuf + (size_t)M_ * 512;   // 1024*512
    float* ctx   = kbuf + (size_t)M_ * 512;   // 1024*256
    float* ct    = ctx  + (size_t)M_ * 256;   // 1024*256
    float* st    = ct   + (size_t)M_ * 256;   // 1024*256
    float* xc    = st   + (size_t)M_ * 256;   // 1024*256
    float* G     = xc   + (size_t)M_ * 256;   // 1024*1024
    float* BB    = G    + (size_t)M_ * 1024;  // 256*1024
    unsigned short* fus_h = (unsigned short*)(BB + (size_t)256 * 1024);
    unsigned short* fus_l = fus_h + (size_t)M_ * 256;          // 1024*256 each
    unsigned short* Wo_h  = fus_l + (size_t)M_ * 256;
    unsigned short* Wo_l  = Wo_h + (size_t)V_ * 256;           // 32000*256 each
    float* winvT = (float*)(Wo_l + (size_t)V_ * 256);          // 65536
    float* bresT = winvT + (size_t)NN_ * D_;                   // 65536
    float* hwinv = bresT + (size_t)NN_ * D_;                   // 1024*256
    float* hcbuf = hwinv + (size_t)M_ * D_;                    // 1024*256

    // merged independent preps: LUT tables, res prep, h prep, Wout split
    k_prep_all<<<dim3(16 + 256 + 1024 + (V_ * 256 / 4 / 256)), dim3(256), 0, stream>>>(
        ids, emb, Wres, Bres, Wout, sin_t, cos_t, winvT, bresT, hwinv, hcbuf, Wo_h, Wo_l);
    k_hscan2<<<dim3(2048 / 64), dim3(64), 0, stream>>>(hwinv, hcbuf, hri, xbuf);
    k_qk<<<dim3(2048), dim3(256), 0, stream>>>(xbuf, wq, bq, wk, bk, sin_t, cos_t, qbuf, kbuf);
    k_attn<<<dim3(M_), dim3(256), 0, stream>>>(qbuf, kbuf, xbuf, ctx);
    // xc = [h_r|h_i] @ Wc^T + bc   (M=1024, N=256, K=512)
    gemm_nt<<<dim3(256 / 64, M_ / 64), dim3(256), 0, stream>>>(hri, 512, Wc, 512, xc, 256, bc, 512, 0, nullptr, nullptr);
    k_res2<<<dim3(M_ / 2), dim3(256), 0, stream>>>(xc, winvT, bresT, ct, st);
    k_pack<<<dim3((M_ * 1024 + 256 * 1024) / 256), dim3(256), 0, stream>>>(ctx, ct, st, Wr, Wi, Wor, Woi, G, BB);
    // fused = G @ BB^T, epilogue writes bf16 hi/lo split directly (M=1024, N=256, K=1024)
    gemm_nt<<<dim3(256 / 64, M_ / 64), dim3(256), 0, stream>>>(G, 1024, BB, 1024, nullptr, 256, nullptr, 1024, 2, fus_h, fus_l);
    // logits = fused @ Wout^T via bf16x3 MFMA, XCD-panel-grouped grid
    gemm_logits3<<<dim3(2048), dim3(256), 0, stream>>>(fus_h, fus_l, Wo_h, Wo_l, out);
}

// Round 7
// 215.163 us; speedup vs baseline: 3.0710x; 1.1168x over previous
//
#include <hip/hip_runtime.h>
#include <math.h>

// ---------------- constants ----------------
#define PHI_F      ((float)1.6180339887498948482045868343656381177)
#define INV_STEP_F ((float)(4096.0 / (2.0 * 3.1415926535897932384626433832795028842)))
#define LUTN 4096
#define B_  8
#define S_  128
#define D_  256
#define H_  8
#define DH_ 32
#define NN_ 256
#define V_  32000
#define M_  (B_ * S_)   // 1024 rows, m = t*8 + b

typedef __attribute__((ext_vector_type(4))) float f32x4;
typedef __attribute__((ext_vector_type(8))) short bf16x8;

// Exact replication of lut_sin_cos (f32, unfused ops, mod-4096 like jnp.mod)
__device__ __forceinline__ void lut_sc(float theta,
                                       const float* __restrict__ st,
                                       const float* __restrict__ ct,
                                       float& s, float& c) {
    float pos  = __fmul_rn(theta, INV_STEP_F);
    float i0f  = floorf(pos);
    float frac = __fsub_rn(pos, i0f);
    int i0 = ((int)i0f) & (LUTN - 1);
    int i1 = (i0 + 1) & (LUTN - 1);
    float w0 = __fsub_rn(1.0f, frac);
    s = __fadd_rn(__fmul_rn(st[i0], w0), __fmul_rn(st[i1], frac));
    c = __fadd_rn(__fmul_rn(ct[i0], w0), __fmul_rn(ct[i1], frac));
}

__device__ __forceinline__ unsigned short f2bf_rne(float x) {
    unsigned u = __float_as_uint(x);
    unsigned r = (u + 0x7FFFu + ((u >> 16) & 1u)) >> 16;
    return (unsigned short)r;
}

__device__ __forceinline__ void split_hl(float x, unsigned short& h, unsigned short& l) {
    h = f2bf_rne(x);
    float hf = __uint_as_float(((unsigned)h) << 16);
    l = f2bf_rne(__fsub_rn(x, hf));
}

// ---------------- K0: merged independent preps ------------------------------
// [0,16) LUT; [16,272) res prep; [272,1296) h prep; [1296,9296) Wout split;
// [9296,9424) Wc split; [9424,9616) BB build+split.
__global__ __launch_bounds__(256) void k_prep_all(
    const int* __restrict__ ids, const float* __restrict__ emb,
    const float* __restrict__ Wres, const float* __restrict__ Bres,
    const float* __restrict__ Wout, const float* __restrict__ Wc,
    const float* __restrict__ Wr, const float* __restrict__ Wi,
    const float* __restrict__ Wor, const float* __restrict__ Woi,
    float* __restrict__ sin_t, float* __restrict__ cos_t,
    float* __restrict__ winvT, float* __restrict__ bresT,
    float* __restrict__ hwinv, float* __restrict__ hcbuf,
    unsigned short* __restrict__ Wo_h, unsigned short* __restrict__ Wo_l,
    unsigned short* __restrict__ Wc_h, unsigned short* __restrict__ Wc_l,
    unsigned short* __restrict__ BB_h, unsigned short* __restrict__ BB_l)
{
    const int blk = blockIdx.x;
    const int tid = threadIdx.x;
    if (blk < 16) {
        int i = blk * 256 + tid;
        double ang = (2.0 * 3.1415926535897932384626433832795028842 * (double)i) / (double)LUTN;
        sin_t[i] = (float)sin(ang);
        cos_t[i] = (float)cos(ang);
    } else if (blk < 272) {
        int i = (blk - 16) * 256 + tid;       // i = n*256+d
        int n = i >> 8, d = i & 255;
        winvT[d * NN_ + n] = 1.0f / (1.0f + fabsf(Wres[i]));
        bresT[d * NN_ + n] = Bres[i];
    } else if (blk < 1296) {
        int m = blk - 272, d = tid;
        int t = m >> 3, b = m & 7;
        int id = ids[b * S_ + t];
        float w  = emb[(size_t)id * (2 * D_) + d];
        float bt = emb[(size_t)id * (2 * D_) + D_ + d];
        hwinv[(size_t)m * D_ + d] = 1.0f / (1.0f + fabsf(w));
        hcbuf[(size_t)m * D_ + d] = 2.0f * (bt + (float)t * PHI_F);
    } else if (blk < 9296) {
        int i = ((blk - 1296) * 256 + tid) * 4;    // < V_*256
        float4 v = *(const float4*)&Wout[i];
        float xs[4] = {v.x, v.y, v.z, v.w};
        ushort hs[4], ls[4];
        #pragma unroll
        for (int j = 0; j < 4; ++j) split_hl(xs[j], hs[j], ls[j]);
        *(ushort4*)&Wo_h[i] = make_ushort4(hs[0], hs[1], hs[2], hs[3]);
        *(ushort4*)&Wo_l[i] = make_ushort4(ls[0], ls[1], ls[2], ls[3]);
    } else if (blk < 9424) {
        int i = ((blk - 9296) * 256 + tid) * 4;    // < 256*512
        float4 v = *(const float4*)&Wc[i];
        float xs[4] = {v.x, v.y, v.z, v.w};
        ushort hs[4], ls[4];
        #pragma unroll
        for (int j = 0; j < 4; ++j) split_hl(xs[j], hs[j], ls[j]);
        *(ushort4*)&Wc_h[i] = make_ushort4(hs[0], hs[1], hs[2], hs[3]);
        *(ushort4*)&Wc_l[i] = make_ushort4(ls[0], ls[1], ls[2], ls[3]);
    } else {
        int i = ((blk - 9424) * 256 + tid) * 4;    // < 256*768, BB[n][k]
        int n = i / 768, k = i % 768;
        float4 v;
        if (k < 256) {
            float4 a = *(const float4*)&Wr[n * 256 + k];
            float4 b = *(const float4*)&Wi[n * 256 + k];
            v.x = a.x + b.x; v.y = a.y + b.y; v.z = a.z + b.z; v.w = a.w + b.w;
        } else if (k < 512) {
            v = *(const float4*)&Wor[n * 256 + (k - 256)];
        } else {
            v = *(const float4*)&Woi[n * 256 + (k - 512)];
        }
        float xs[4] = {v.x, v.y, v.z, v.w};
        ushort hs[4], ls[4];
        #pragma unroll
        for (int j = 0; j < 4; ++j) split_hl(xs[j], hs[j], ls[j]);
        *(ushort4*)&BB_h[i] = make_ushort4(hs[0], hs[1], hs[2], hs[3]);
        *(ushort4*)&BB_l[i] = make_ushort4(ls[0], ls[1], ls[2], ls[3]);
    }
}

// ---------------- K1: sequential h-recurrence (angle form) ------------------
// writes hri as bf16 hi/lo split directly: [m][k] k<256 = h_r, k>=256 = h_i
__global__ __launch_bounds__(64) void k_hscan2(
    const float* __restrict__ winv, const float* __restrict__ cbuf,
    unsigned short* __restrict__ hri_h, unsigned short* __restrict__ hri_l,
    float* __restrict__ xbuf)
{
    int e = blockIdx.x * 64 + threadIdx.x;   // 0..2047
    int b = e >> 8, d = e & 255;
    float x = 0.f;
    #pragma unroll 4
    for (int t = 0; t < S_; ++t) {
        int m = (t << 3) | b;
        float wi = winv[(size_t)m * D_ + d];
        float c  = cbuf[(size_t)m * D_ + d];
        float u  = fmaf(x, wi, c);
        float s, co;
        __sincosf(u, &s, &co);
        x = co + s;
        ushort hh, hl, sh, sl;
        split_hl(co, hh, hl);
        split_hl(s,  sh, sl);
        hri_h[(size_t)m * 512 + d]       = hh;
        hri_l[(size_t)m * 512 + d]       = hl;
        hri_h[(size_t)m * 512 + 256 + d] = sh;
        hri_l[(size_t)m * 512 + 256 + d] = sl;
        xbuf[(size_t)m * D_ + d]         = x;
    }
}

// ---------------- K2: build Q/K phase vectors ----------------
__global__ void k_qk(const float* __restrict__ xbuf,
                     const float* __restrict__ wq, const float* __restrict__ bq,
                     const float* __restrict__ wk, const float* __restrict__ bk,
                     const float* __restrict__ sin_t, const float* __restrict__ cos_t,
                     float* __restrict__ qbuf, float* __restrict__ kbuf)
{
    int i = blockIdx.x * 256 + threadIdx.x;
    const int half = S_ * B_ * H_ * DH_;
    bool isq = (i < half);
    int r = isq ? i : i - half;
    if (r >= half) return;
    int j = r & 31;
    int h = (r >> 5) & 7;
    int b = (r >> 8) & 7;
    int t = r >> 11;
    int m = (t << 3) | b;
    float xv = xbuf[(size_t)m * D_ + h * DH_ + j];
    const float* W  = isq ? wq : wk;
    const float* Bv = isq ? bq : bk;
    float wl = __fadd_rn(1.0f, fabsf(W[h * DH_ + j]));
    float th = __fadd_rn(__fdiv_rn(xv, wl), Bv[h * DH_ + j]);
    if (isq) th = __fadd_rn(th, __fmul_rn((float)t, PHI_F));
    float s, c;
    lut_sc(th, sin_t, cos_t, s, c);
    float* out = isq ? qbuf : kbuf;
    out[(size_t)m * (2 * DH_ * H_) + h * 64 + j]      = c;
    out[(size_t)m * (2 * DH_ * H_) + h * 64 + 32 + j] = s;
}

// ---------------- K3: causal phase attention -> G[:,0:256] (hi/lo) ----------
__global__ __launch_bounds__(256) void k_attn(
    const float* __restrict__ qbuf, const float* __restrict__ kbuf,
    const float* __restrict__ xbuf,
    unsigned short* __restrict__ G_h, unsigned short* __restrict__ G_l)
{
    int m = blockIdx.x;
    int t = m >> 3, b = m & 7;
    int tid = threadIdx.x;
    if (t == 0) {
        G_h[(size_t)m * 768 + tid] = 0;
        G_l[(size_t)m * 768 + tid] = 0;
        return;
    }
    __shared__ float qs[512];
    __shared__ float sc[8][128];
    __shared__ float denom[8];
    __shared__ float wsum[128];
    qs[tid]       = qbuf[(size_t)m * 512 + tid];
    qs[tid + 256] = qbuf[(size_t)m * 512 + 256 + tid];
    __syncthreads();
    int h = tid & 7;
    for (int s = tid >> 3; s < t; s += 32) {
        const float* kk = kbuf + (size_t)((s << 3) | b) * 512 + h * 64;
        const float* qq = qs + h * 64;
        float dot = 0.f;
        #pragma unroll
        for (int e = 0; e < 64; ++e) dot += qq[e] * kk[e];
        sc[h][s] = dot * 0.125f;
    }
    __syncthreads();
    if (tid < 8) {
        float mx = -1e30f;
        for (int s = 0; s < t; ++s) mx = fmaxf(mx, sc[tid][s]);
        float dn = 0.f;
        for (int s = 0; s < t; ++s) { float e = expf(sc[tid][s] - mx); sc[tid][s] = e; dn += e; }
        denom[tid] = dn;
    }
    __syncthreads();
    if (tid < t) {
        float wv = 0.f;
        #pragma unroll
        for (int hh = 0; hh < 8; ++hh) wv += sc[hh][tid] / denom[hh];
        wsum[tid] = wv;
    }
    __syncthreads();
    float a0 = 0.f, a1 = 0.f, a2 = 0.f, a3 = 0.f;
    int s = 0;
    for (; s + 4 <= t; s += 4) {
        a0 += wsum[s + 0] * xbuf[(size_t)(((s + 0) << 3) | b) * D_ + tid];
        a1 += wsum[s + 1] * xbuf[(size_t)(((s + 1) << 3) | b) * D_ + tid];
        a2 += wsum[s + 2] * xbuf[(size_t)(((s + 2) << 3) | b) * D_ + tid];
        a3 += wsum[s + 3] * xbuf[(size_t)(((s + 3) << 3) | b) * D_ + tid];
    }
    for (; s < t; ++s) a0 += wsum[s] * xbuf[(size_t)((s << 3) | b) * D_ + tid];
    float v = (a0 + a1) + (a2 + a3);
    ushort hu, lu;
    split_hl(v, hu, lu);
    G_h[(size_t)m * 768 + tid] = hu;
    G_l[(size_t)m * 768 + tid] = lu;
}

// ---------------- K4: resonant layer -> G[:,256:768] (hi/lo) ----------------
__global__ __launch_bounds__(256) void k_res2(
    const float* __restrict__ xc,
    const float* __restrict__ winvT, const float* __restrict__ bresT,
    unsigned short* __restrict__ G_h, unsigned short* __restrict__ G_l)
{
    __shared__ float s_xc0[D_], s_xc1[D_];
    const int m0 = blockIdx.x * 2;
    const int tid = threadIdx.x;
    s_xc0[tid] = xc[(size_t)m0 * D_ + tid];
    s_xc1[tid] = xc[(size_t)(m0 + 1) * D_ + tid];
    __syncthreads();
    const int n = tid;
    const float tp = __fmul_rn((float)(m0 >> 3), PHI_F);
    float cs0 = 0.f, ss0 = 0.f, cs1 = 0.f, ss1 = 0.f;
    #pragma unroll 4
    for (int d = 0; d < D_; ++d) {
        float wi = winvT[d * NN_ + n];
        float bt = bresT[d * NN_ + n] + tp;
        float th0 = fmaf(s_xc0[d], wi, bt);
        float th1 = fmaf(s_xc1[d], wi, bt);
        cs0 += __cosf(th0); ss0 += __sinf(th0);
        cs1 += __cosf(th1); ss1 += __sinf(th1);
    }
    ushort h0, l0, h1, l1, h2, l2, h3, l3;
    split_hl(cs0, h0, l0); split_hl(ss0, h1, l1);
    split_hl(cs1, h2, l2); split_hl(ss1, h3, l3);
    G_h[(size_t)m0 * 768 + 256 + n] = h0; G_l[(size_t)m0 * 768 + 256 + n] = l0;
    G_h[(size_t)m0 * 768 + 512 + n] = h1; G_l[(size_t)m0 * 768 + 512 + n] = l1;
    G_h[(size_t)(m0 + 1) * 768 + 256 + n] = h2; G_l[(size_t)(m0 + 1) * 768 + 256 + n] = l2;
    G_h[(size_t)(m0 + 1) * 768 + 512 + n] = h3; G_l[(size_t)(m0 + 1) * 768 + 512 + n] = l3;
}

// ---------------- gemm_small: MFMA bf16 3-term, 128x128 tile, generic K -----
// C[m][n] = sum_k A[m][k]*B[n][k]; mode 0: f32 out (+bias); mode 2: hi/lo split out
__global__ __launch_bounds__(256) void gemm_small(
    const unsigned short* __restrict__ Ah, const unsigned short* __restrict__ Al, int lda,
    const unsigned short* __restrict__ Bh, const unsigned short* __restrict__ Bl, int ldb,
    int K, const float* __restrict__ bias,
    float* __restrict__ outF, int ldc, int mode,
    unsigned short* __restrict__ Oh, unsigned short* __restrict__ Ol)
{
    __shared__ unsigned short sAh[128 * 64], sAl[128 * 64];
    __shared__ unsigned short sBh[128 * 64], sBl[128 * 64];
    const int n0 = blockIdx.x * 128;
    const int m0 = blockIdx.y * 128;
    const int tid  = threadIdx.x;
    const int lane = tid & 63;
    const int wv   = tid >> 6;
    const int wr   = wv >> 1, wc = wv & 1;
    f32x4 acc[4][4] = {};

    for (int k0 = 0; k0 < K; k0 += 64) {
        #pragma unroll
        for (int q = 0; q < 4; ++q) {
            int idx  = q * 256 + tid;
            int row  = idx >> 3;
            int slot = (idx & 7) ^ (row & 7);
            int ldsbase = (q * 256 + wv * 64) * 8;
            size_t ga = (size_t)(m0 + row) * lda + k0 + slot * 8;
            size_t gb = (size_t)(n0 + row) * ldb + k0 + slot * 8;
            __builtin_amdgcn_global_load_lds(
                (const __attribute__((address_space(1))) void*)(Ah + ga),
                (__attribute__((address_space(3))) void*)(sAh + ldsbase), 16, 0, 0);
            __builtin_amdgcn_global_load_lds(
                (const __attribute__((address_space(1))) void*)(Al + ga),
                (__attribute__((address_space(3))) void*)(sAl + ldsbase), 16, 0, 0);
            __builtin_amdgcn_global_load_lds(
                (const __attribute__((address_space(1))) void*)(Bh + gb),
                (__attribute__((address_space(3))) void*)(sBh + ldsbase), 16, 0, 0);
            __builtin_amdgcn_global_load_lds(
                (const __attribute__((address_space(1))) void*)(Bl + gb),
                (__attribute__((address_space(3))) void*)(sBl + ldsbase), 16, 0, 0);
        }
        __syncthreads();

        #pragma unroll
        for (int ks = 0; ks < 2; ++ks) {
            const int kg = ks * 4 + (lane >> 4);
            bf16x8 afh[4], afl[4], bfh[4], bfl[4];
            #pragma unroll
            for (int mi = 0; mi < 4; ++mi) {
                int row  = wr * 64 + mi * 16 + (lane & 15);
                int slot = kg ^ (row & 7);
                afh[mi] = *(const bf16x8*)&sAh[row * 64 + slot * 8];
                afl[mi] = *(const bf16x8*)&sAl[row * 64 + slot * 8];
            }
            #pragma unroll
            for (int nj = 0; nj < 4; ++nj) {
                int row  = wc * 64 + nj * 16 + (lane & 15);
                int slot = kg ^ (row & 7);
                bfh[nj] = *(const bf16x8*)&sBh[row * 64 + slot * 8];
                bfl[nj] = *(const bf16x8*)&sBl[row * 64 + slot * 8];
            }
            #pragma unroll
            for (int mi = 0; mi < 4; ++mi)
                #pragma unroll
                for (int nj = 0; nj < 4; ++nj) {
                    acc[mi][nj] = __builtin_amdgcn_mfma_f32_16x16x32_bf16(afh[mi], bfh[nj], acc[mi][nj], 0, 0, 0);
                    acc[mi][nj] = __builtin_amdgcn_mfma_f32_16x16x32_bf16(afh[mi], bfl[nj], acc[mi][nj], 0, 0, 0);
                    acc[mi][nj] = __builtin_amdgcn_mfma_f32_16x16x32_bf16(afl[mi], bfh[nj], acc[mi][nj], 0, 0, 0);
                }
        }
        __syncthreads();
    }

    #pragma unroll
    for (int mi = 0; mi < 4; ++mi)
        #pragma unroll
        for (int nj = 0; nj < 4; ++nj)
            #pragma unroll
            for (int r = 0; r < 4; ++r) {
                int m = m0 + wr * 64 + mi * 16 + (lane >> 4) * 4 + r;
                int n = n0 + wc * 64 + nj * 16 + (lane & 15);
                float v = acc[mi][nj][r];
                if (mode == 0) {
                    outF[(size_t)m * ldc + n] = v + bias[n];
                } else {
                    ushort hu, lu;
                    split_hl(v, hu, lu);
                    Oh[(size_t)m * ldc + n] = hu;
                    Ol[(size_t)m * ldc + n] = lu;
                }
            }
}

// ---------------- K7 v3: logits GEMM, XCD-panel-grouped ordering ------------
__global__ __launch_bounds__(256) void gemm_logits3(
    const unsigned short* __restrict__ Ah, const unsigned short* __restrict__ Al,
    const unsigned short* __restrict__ Bh, const unsigned short* __restrict__ Bl,
    float* __restrict__ out)
{
    const int blk = blockIdx.x;
    const int r = blk & 7, mt = (blk >> 3) & 7, j = blk >> 6;
    const int p = j * 8 + r;
    if (p >= V_ / 128) return;
    const int n0 = p * 128;
    const int m0 = mt * 128;

    __shared__ unsigned short sAh[128 * 64], sAl[128 * 64];
    __shared__ unsigned short sBh[128 * 64], sBl[128 * 64];
    const int tid  = threadIdx.x;
    const int lane = tid & 63;
    const int wv   = tid >> 6;
    const int wr   = wv >> 1, wc = wv & 1;
    f32x4 acc[4][4] = {};

    for (int k0 = 0; k0 < 256; k0 += 64) {
        #pragma unroll
        for (int q = 0; q < 4; ++q) {
            int idx  = q * 256 + tid;
            int row  = idx >> 3;
            int slot = (idx & 7) ^ (row & 7);
            int ldsbase = (q * 256 + wv * 64) * 8;
            size_t ga = (size_t)(m0 + row) * 256 + k0 + slot * 8;
            size_t gb = (size_t)(n0 + row) * 256 + k0 + slot * 8;
            __builtin_amdgcn_global_load_lds(
                (const __attribute__((address_space(1))) void*)(Ah + ga),
                (__attribute__((address_space(3))) void*)(sAh + ldsbase), 16, 0, 0);
            __builtin_amdgcn_global_load_lds(
                (const __attribute__((address_space(1))) void*)(Al + ga),
                (__attribute__((address_space(3))) void*)(sAl + ldsbase), 16, 0, 0);
            __builtin_amdgcn_global_load_lds(
                (const __attribute__((address_space(1))) void*)(Bh + gb),
                (__attribute__((address_space(3))) void*)(sBh + ldsbase), 16, 0, 0);
            __builtin_amdgcn_global_load_lds(
                (const __attribute__((address_space(1))) void*)(Bl + gb),
                (__attribute__((address_space(3))) void*)(sBl + ldsbase), 16, 0, 0);
        }
        __syncthreads();

        #pragma unroll
        for (int ks = 0; ks < 2; ++ks) {
            const int kg = ks * 4 + (lane >> 4);
            bf16x8 afh[4], afl[4], bfh[4], bfl[4];
            #pragma unroll
            for (int mi = 0; mi < 4; ++mi) {
                int row  = wr * 64 + mi * 16 + (lane & 15);
                int slot = kg ^ (row & 7);
                afh[mi] = *(const bf16x8*)&sAh[row * 64 + slot * 8];
                afl[mi] = *(const bf16x8*)&sAl[row * 64 + slot * 8];
            }
            #pragma unroll
            for (int nj = 0; nj < 4; ++nj) {
                int row  = wc * 64 + nj * 16 + (lane & 15);
                int slot = kg ^ (row & 7);
                bfh[nj] = *(const bf16x8*)&sBh[row * 64 + slot * 8];
                bfl[nj] = *(const bf16x8*)&sBl[row * 64 + slot * 8];
            }
            #pragma unroll
            for (int mi = 0; mi < 4; ++mi)
                #pragma unroll
                for (int nj = 0; nj < 4; ++nj) {
                    acc[mi][nj] = __builtin_amdgcn_mfma_f32_16x16x32_bf16(afh[mi], bfh[nj], acc[mi][nj], 0, 0, 0);
                    acc[mi][nj] = __builtin_amdgcn_mfma_f32_16x16x32_bf16(afh[mi], bfl[nj], acc[mi][nj], 0, 0, 0);
                    acc[mi][nj] = __builtin_amdgcn_mfma_f32_16x16x32_bf16(afl[mi], bfh[nj], acc[mi][nj], 0, 0, 0);
                }
        }
        __syncthreads();
    }

    #pragma unroll
    for (int mi = 0; mi < 4; ++mi)
        #pragma unroll
        for (int nj = 0; nj < 4; ++nj)
            #pragma unroll
            for (int rr = 0; rr < 4; ++rr) {
                int m = m0 + wr * 64 + mi * 16 + (lane >> 4) * 4 + rr;
                int n = n0 + wc * 64 + nj * 16 + (lane & 15);
                int orow = (m & 7) * S_ + (m >> 3);
                out[(size_t)orow * V_ + n] = acc[mi][nj][rr];
            }
}

// ---------------- launcher ----------------
extern "C" void kernel_launch(void* const* d_in, const int* in_sizes, int n_in,
                              void* d_out, int out_size, void* d_ws, size_t ws_size,
                              hipStream_t stream)
{
    const int*   ids  = (const int*)d_in[0];
    const float* emb  = (const float*)d_in[1];
    const float* wq   = (const float*)d_in[2];
    const float* bq   = (const float*)d_in[3];
    const float* wk   = (const float*)d_in[4];
    const float* bk   = (const float*)d_in[5];
    const float* Wr   = (const float*)d_in[6];
    const float* Wi   = (const float*)d_in[7];
    const float* Wc   = (const float*)d_in[8];
    const float* bc   = (const float*)d_in[9];
    const float* Wres = (const float*)d_in[10];
    const float* Bres = (const float*)d_in[11];
    const float* Wor  = (const float*)d_in[12];
    const float* Woi  = (const float*)d_in[13];
    const float* Wout = (const float*)d_in[14];
    float* out = (float*)d_out;
    float* ws  = (float*)d_ws;

    // f32 region
    float* sin_t = ws;                         // 4096
    float* cos_t = sin_t + LUTN;               // 4096
    float* xbuf  = cos_t + LUTN;               // 1024*256
    float* qbuf  = xbuf + (size_t)M_ * 256;    // 1024*512
    float* kbuf  = qbuf + (size_t)M_ * 512;    // 1024*512
    float* xc    = kbuf + (size_t)M_ * 512;    // 1024*256
    float* winvT = xc   + (size_t)M_ * 256;    // 65536
    float* bresT = winvT + (size_t)NN_ * D_;   // 65536
    float* hwinv = bresT + (size_t)NN_ * D_;   // 1024*256
    float* hcbuf = hwinv + (size_t)M_ * D_;    // 1024*256
    // ushort region
    unsigned short* us = (unsigned short*)(hcbuf + (size_t)M_ * D_);
    unsigned short* hri_h = us;                       us += (size_t)M_ * 512;
    unsigned short* hri_l = us;                       us += (size_t)M_ * 512;
    unsigned short* G_h   = us;                       us += (size_t)M_ * 768;
    unsigned short* G_l   = us;                       us += (size_t)M_ * 768;
    unsigned short* BB_h  = us;                       us += (size_t)256 * 768;
    unsigned short* BB_l  = us;                       us += (size_t)256 * 768;
    unsigned short* Wc_h  = us;                       us += (size_t)256 * 512;
    unsigned short* Wc_l  = us;                       us += (size_t)256 * 512;
    unsigned short* fus_h = us;                       us += (size_t)M_ * 256;
    unsigned short* fus_l = us;                       us += (size_t)M_ * 256;
    unsigned short* Wo_h  = us;                       us += (size_t)V_ * 256;
    unsigned short* Wo_l  = us;

    k_prep_all<<<dim3(9616), dim3(256), 0, stream>>>(
        ids, emb, Wres, Bres, Wout, Wc, Wr, Wi, Wor, Woi,
        sin_t, cos_t, winvT, bresT, hwinv, hcbuf,
        Wo_h, Wo_l, Wc_h, Wc_l, BB_h, BB_l);
    k_hscan2<<<dim3(2048 / 64), dim3(64), 0, stream>>>(hwinv, hcbuf, hri_h, hri_l, xbuf);
    k_qk<<<dim3(2048), dim3(256), 0, stream>>>(xbuf, wq, bq, wk, bk, sin_t, cos_t, qbuf, kbuf);
    k_attn<<<dim3(M_), dim3(256), 0, stream>>>(qbuf, kbuf, xbuf, G_h, G_l);
    // xc = [h_r|h_i] @ Wc^T + bc   (M=1024, N=256, K=512) via MFMA
    gemm_small<<<dim3(2, 8), dim3(256), 0, stream>>>(
        hri_h, hri_l, 512, Wc_h, Wc_l, 512, 512, bc, xc, 256, 0, nullptr, nullptr);
    k_res2<<<dim3(M_ / 2), dim3(256), 0, stream>>>(xc, winvT, bresT, G_h, G_l);
    // fused = G @ BB^T  (M=1024, N=256, K=768) via MFMA, epilogue hi/lo split
    gemm_small<<<dim3(2, 8), dim3(256), 0, stream>>>(
        G_h, G_l, 768, BB_h, BB_l, 768, 768, nullptr, nullptr, 256, 2, fus_h, fus_l);
    // logits = fused @ Wout^T via bf16x3 MFMA, XCD-panel-grouped grid
    gemm_logits3<<<dim3(2048), dim3(256), 0, stream>>>(fus_h, fus_l, Wo_h, Wo_l, out);
}